// Round 3
// baseline (674.029 us; speedup 1.0000x reference)
//
#include <hip/hip_runtime.h>
#include <hip/hip_bf16.h>
#include <hip/hip_cooperative_groups.h>

#define FIN 256
#define HID 64
#define EMB 2
#define BKB 9            // bucket = dst >> 9 (512 nodes per bucket)
#define BKSZ 512
#define CGRID 512        // cooperative grid size = binning chunk count
#define WPREP 8          // blocks in phase-1 that pre-pack W1

typedef __bf16 bf16x8 __attribute__((ext_vector_type(8)));
typedef float  f32x16 __attribute__((ext_vector_type(16)));
typedef unsigned short u16x8 __attribute__((ext_vector_type(8)));

// ---- bf16 helpers (RNE) ----
static __device__ __forceinline__ unsigned short f2bf(float f) {
    union { float f; unsigned int u; } v; v.f = f;
    unsigned int u = v.u;
    unsigned int r = (u + 0x7fffu + ((u >> 16) & 1u)) >> 16;
    return (unsigned short)r;
}
static __device__ __forceinline__ float bf2f(unsigned short h) {
    union { unsigned int u; float f; } v; v.u = ((unsigned int)h) << 16;
    return v.f;
}

// ---------------------------------------------------------------------------
// Cooperative CSR-build chain: 4 phases, 3 grid syncs, one launch.
//   P0: per-block coarse histogram (dst>>9) -> counts[bucket][block]
//   P1: per-bucket exclusive scan of 512 per-block counts (+ W1 pre-pack,
//       + zero sums/cntf/done)
//   P2: scatter packed (src<<9|dst&511); every block locally scans btot in LDS
//       (removes the old 1-block scan_tot kernel)
//   P3: per-bucket build: degree/dinv/rowptr + bucket-local CSR scatter
// All arithmetic identical to the round-1 kernels -> bit-identical output.
struct CoopArgs {
    const int* src; const int* dst;
    int* counts; int* btot;
    unsigned* ebuf; int* csr; int* rowptr; float* dinv;
    const float* W1; __bf16* Bh; __bf16* Bl;
    float* pool;       // sums[2G] | cntf[G] | done (zeroed in P1)
    int E, chunk, NBK, N, G;
};

__global__ __launch_bounds__(256, 2) void coop_chain_kernel(CoopArgs a) {
    namespace cg = cooperative_groups;
    cg::grid_group grid = cg::this_grid();
    __shared__ int hist[BKSZ];     // P0 coarse hist / P2 sbase / P3 fine hist
    __shared__ int scanb[256];     // scan buffer
    __shared__ int cur[BKSZ];      // P2 scatter cursors / P3 local cursors

    const int bi  = blockIdx.x;
    const int tid = threadIdx.x;
    const int NBK = a.NBK;

    // ---------------- P0: coarse histogram ----------------
    for (int b = tid; b < NBK; b += 256) hist[b] = 0;
    __syncthreads();
    {
        int e0 = bi * a.chunk, e1 = min(e0 + a.chunk, a.E);
        if (e0 < e1) {
            const int4* d4 = (const int4*)(a.dst + e0);
            int nv = (e1 - e0) >> 2;
            for (int i = tid; i < nv; i += 256) {
                int4 v = d4[i];
                atomicAdd(&hist[v.x >> BKB], 1);
                atomicAdd(&hist[v.y >> BKB], 1);
                atomicAdd(&hist[v.z >> BKB], 1);
                atomicAdd(&hist[v.w >> BKB], 1);
            }
            for (int i = e0 + (nv << 2) + tid; i < e1; i += 256)
                atomicAdd(&hist[a.dst[i] >> BKB], 1);
        }
    }
    __syncthreads();
    for (int b = tid; b < NBK; b += 256) a.counts[b * CGRID + bi] = hist[b];
    __threadfence();
    grid.sync();

    // ---------------- P1: per-bucket scan (+ W pack + zero) ----------------
    if (bi < NBK) {
        int c0 = a.counts[bi * CGRID + 2 * tid];
        int c1 = a.counts[bi * CGRID + 2 * tid + 1];
        int pair = c0 + c1;
        scanb[tid] = pair;
        __syncthreads();
        for (int off = 1; off < 256; off <<= 1) {
            int t = (tid >= off) ? scanb[tid - off] : 0;
            __syncthreads();
            scanb[tid] += t;
            __syncthreads();
        }
        int base = scanb[tid] - pair;                 // exclusive (pairwise)
        a.counts[bi * CGRID + 2 * tid]     = base;
        a.counts[bi * CGRID + 2 * tid + 1] = base + c0;
        if (tid == 255) a.btot[bi] = scanb[255];
    } else if (bi < NBK + WPREP) {
        // W1 pre-pack into bf16 hi/lo MFMA-fragment order (as round-1):
        // vec v = ((ch*8+g)*64+m), elem q: k = ch*64+(g&3)*16+(m>>5)*8+q,
        // n = (g>>2)*32+(m&31)
        int t = (bi - NBK) * 256 + tid;               // 0..2047
        int ch = t >> 9, g = (t >> 6) & 7, m = t & 63;
        int kbase = ch * 64 + (g & 3) * 16 + ((m >> 5) << 3);
        int n = ((g >> 2) << 5) + (m & 31);
        bf16x8 hi, lo;
        #pragma unroll
        for (int q = 0; q < 8; ++q) {
            float w = a.W1[(size_t)(kbase + q) * HID + n];
            __bf16 h = (__bf16)w;
            hi[q] = h; lo[q] = (__bf16)(w - (float)h);
        }
        *(bf16x8*)&a.Bh[(size_t)t * 8] = hi;
        *(bf16x8*)&a.Bl[(size_t)t * 8] = lo;
    } else if (bi == NBK + WPREP) {
        for (int i = tid; i < 3 * a.G + 1; i += 256) a.pool[i] = 0.f;
    }
    __threadfence();
    grid.sync();

    // ---------------- P2: scatter (local bucketBase scan) ----------------
    {
        int v = (tid < NBK) ? a.btot[tid] : 0;
        scanb[tid] = v;
        __syncthreads();
        for (int off = 1; off < 256; off <<= 1) {
            int t = (tid >= off) ? scanb[tid - off] : 0;
            __syncthreads();
            scanb[tid] += t;
            __syncthreads();
        }
        if (tid < NBK) hist[tid] = scanb[tid] - v;    // sbase[b]
        __syncthreads();
        for (int b = tid; b < NBK; b += 256)
            cur[b] = hist[b] + a.counts[b * CGRID + bi];
        __syncthreads();

        int e0 = bi * a.chunk, e1 = min(e0 + a.chunk, a.E);
        if (e0 < e1) {
            const int4* s4 = (const int4*)(a.src + e0);
            const int4* d4 = (const int4*)(a.dst + e0);
            int nv = (e1 - e0) >> 2;
            for (int i = tid; i < nv; i += 256) {
                int4 sv = s4[i], dv = d4[i];
                int b0 = dv.x >> BKB;
                int p0 = atomicAdd(&cur[b0], 1);
                a.ebuf[p0] = ((unsigned)sv.x << BKB) | (unsigned)(dv.x & (BKSZ - 1));
                int b1 = dv.y >> BKB;
                int p1 = atomicAdd(&cur[b1], 1);
                a.ebuf[p1] = ((unsigned)sv.y << BKB) | (unsigned)(dv.y & (BKSZ - 1));
                int b2 = dv.z >> BKB;
                int p2 = atomicAdd(&cur[b2], 1);
                a.ebuf[p2] = ((unsigned)sv.z << BKB) | (unsigned)(dv.z & (BKSZ - 1));
                int b3 = dv.w >> BKB;
                int p3 = atomicAdd(&cur[b3], 1);
                a.ebuf[p3] = ((unsigned)sv.w << BKB) | (unsigned)(dv.w & (BKSZ - 1));
            }
            for (int i = e0 + (nv << 2) + tid; i < e1; i += 256) {
                int s = a.src[i], d = a.dst[i];
                int b = d >> BKB;
                int pos = atomicAdd(&cur[b], 1);
                a.ebuf[pos] = ((unsigned)s << BKB) | (unsigned)(d & (BKSZ - 1));
            }
        }
    }
    __threadfence();
    grid.sync();

    // ---------------- P3: build (only blocks < NBK) ----------------
    if (bi < NBK) {
        // local bucketBase scan again (cheap, avoids a global array)
        int v = (tid < NBK) ? a.btot[tid] : 0;
        scanb[tid] = v;
        __syncthreads();
        for (int off = 1; off < 256; off <<= 1) {
            int t = (tid >= off) ? scanb[tid - off] : 0;
            __syncthreads();
            scanb[tid] += t;
            __syncthreads();
        }
        const int r1 = scanb[bi];                     // inclusive
        const int r0 = r1 - a.btot[bi];
        const int nb0 = bi * BKSZ;
        __syncthreads();

        hist[tid] = 0; hist[tid + 256] = 0;
        __syncthreads();
        for (int i = r0 + tid; i < r1; i += 256)
            atomicAdd(&hist[a.ebuf[i] & (BKSZ - 1u)], 1);
        __syncthreads();

        int h0 = hist[2 * tid], h1 = hist[2 * tid + 1];
        if (nb0 + 2 * tid < a.N)     a.dinv[nb0 + 2 * tid]     = rsqrtf((float)h0 + 1.f);
        if (nb0 + 2 * tid + 1 < a.N) a.dinv[nb0 + 2 * tid + 1] = rsqrtf((float)h1 + 1.f);
        scanb[tid] = h0 + h1;
        __syncthreads();
        for (int off = 1; off < 256; off <<= 1) {
            int t = (tid >= off) ? scanb[tid - off] : 0;
            __syncthreads();
            scanb[tid] += t;
            __syncthreads();
        }
        int base0 = scanb[tid] - (h0 + h1);
        int o0 = base0, o1 = base0 + h0;
        cur[2 * tid] = o0; cur[2 * tid + 1] = o1;
        if (nb0 + 2 * tid < a.N)     a.rowptr[nb0 + 2 * tid]     = r0 + o0;
        if (nb0 + 2 * tid + 1 < a.N) a.rowptr[nb0 + 2 * tid + 1] = r0 + o1;
        if (nb0 + BKSZ >= a.N && tid == 0) a.rowptr[a.N] = a.E;
        __syncthreads();
        for (int i = r0 + tid; i < r1; i += 256) {
            unsigned u = a.ebuf[i];
            int loc = (int)(u & (BKSZ - 1u));
            int p = atomicAdd(&cur[loc], 1);
            a.csr[r0 + p] = (int)(u >> BKB);
        }
    }
}

// ---------------------------------------------------------------------------
// h1' = dinv * (x @ W1) via MFMA (bf16 hi/lo split: xh*wh + xh*wl + xl*wh).
// Block = 64-node x 64-feat tile, 4 waves = four 32x32 quadrants. bf16 store.
// B fragments pre-packed (hi/lo, MFMA order) in global: 32 KB, L2-hot.
__global__ __launch_bounds__(256) void gemm1_kernel(
        const float* __restrict__ x,
        const __bf16* __restrict__ Bh, const __bf16* __restrict__ Bl,
        const float* __restrict__ dinv, unsigned short* __restrict__ h1b, int N) {
    __shared__ __align__(16) __bf16 A_hi[2 * 4 * 64 * 8];
    __shared__ __align__(16) __bf16 A_lo[2 * 4 * 64 * 8];

    const int tid = threadIdx.x;
    const int base = blockIdx.x * 64;
    const int w = tid >> 6;
    const int l = tid & 63;
    const int mg = w >> 1, ng = w & 1;

    const bf16x8* Bh8 = (const bf16x8*)Bh;
    const bf16x8* Bl8 = (const bf16x8*)Bl;

    f32x16 acc = {};

    const int r  = tid & 63;
    const int ks = tid >> 6;
    const int rl = r & 31, rh = r >> 5;

    for (int ch = 0; ch < 4; ++ch) {
        const int ck0 = ch * 64;
        __syncthreads();
        {
            int row = base + r;
            float f[16];
            if (row < N) {
                const float* xp = &x[(size_t)row * FIN + ck0 + ks * 16];
                float4 v0 = *(const float4*)(xp + 0);
                float4 v1 = *(const float4*)(xp + 4);
                float4 v2 = *(const float4*)(xp + 8);
                float4 v3 = *(const float4*)(xp + 12);
                f[0]=v0.x; f[1]=v0.y; f[2]=v0.z; f[3]=v0.w;
                f[4]=v1.x; f[5]=v1.y; f[6]=v1.z; f[7]=v1.w;
                f[8]=v2.x; f[9]=v2.y; f[10]=v2.z; f[11]=v2.w;
                f[12]=v3.x; f[13]=v3.y; f[14]=v3.z; f[15]=v3.w;
            } else {
                #pragma unroll
                for (int q = 0; q < 16; ++q) f[q] = 0.f;
            }
            bf16x8 ha, hb, la, lb;
            #pragma unroll
            for (int q = 0; q < 8; ++q) {
                __bf16 h0 = (__bf16)f[q];
                ha[q] = h0; la[q] = (__bf16)(f[q] - (float)h0);
                __bf16 h1v = (__bf16)f[q + 8];
                hb[q] = h1v; lb[q] = (__bf16)(f[q + 8] - (float)h1v);
            }
            int ra = ((rh * 4 + ks) * 64 + rl) * 8;
            int rb = ((rh * 4 + ks) * 64 + 32 + rl) * 8;
            *(bf16x8*)&A_hi[ra] = ha; *(bf16x8*)&A_hi[rb] = hb;
            *(bf16x8*)&A_lo[ra] = la; *(bf16x8*)&A_lo[rb] = lb;
        }
        __syncthreads();

        #pragma unroll
        for (int s = 0; s < 4; ++s) {
            bf16x8 a_h = *(const bf16x8*)&A_hi[((mg * 4 + s) * 64 + l) * 8];
            bf16x8 a_l = *(const bf16x8*)&A_lo[((mg * 4 + s) * 64 + l) * 8];
            int bv = (ch * 8 + ng * 4 + s) * 64 + l;
            bf16x8 b_h = Bh8[bv];
            bf16x8 b_l = Bl8[bv];
            acc = __builtin_amdgcn_mfma_f32_32x32x16_bf16(a_h, b_h, acc, 0, 0, 0);
            acc = __builtin_amdgcn_mfma_f32_32x32x16_bf16(a_h, b_l, acc, 0, 0, 0);
            acc = __builtin_amdgcn_mfma_f32_32x32x16_bf16(a_l, b_h, acc, 0, 0, 0);
        }
    }

    const int col = l & 31;
    const int rbase = 4 * (l >> 5);
    #pragma unroll
    for (int reg = 0; reg < 16; ++reg) {
        int row = (reg & 3) + 8 * (reg >> 2) + rbase;
        int node = base + mg * 32 + row;
        if (node < N)
            h1b[(size_t)node * HID + ng * 32 + col] = f2bf(acc[reg] * dinv[node]);
    }
}

// ---------------------------------------------------------------------------
// Fused layer-1 CSR gather (pure sum of pre-scaled h1') + b1 + ReLU + (64->2).
// 8 nodes per wave: 8 lanes/node, lane = 8 feats (ushort8 = 16 B/lane gather).
__global__ __launch_bounds__(256) void agg1_layer2_kernel(
        const int* __restrict__ rowptr, const int* __restrict__ csr,
        const unsigned short* __restrict__ h1b,
        const float* __restrict__ dinv, const float* __restrict__ b1,
        const float* __restrict__ W2, float* __restrict__ h2, int N) {
    long t = (long)blockIdx.x * blockDim.x + threadIdx.x;
    int n = (int)(t >> 3);
    int li = threadIdx.x & 7;
    if (n >= N) return;
    const u16x8* h18 = (const u16x8*)h1b;    // row = 8 vectors x 8 feats

    float di = dinv[n];
    u16x8 sl = h18[(size_t)n * 8 + li];      // self term (h1' pre-scaled)
    float v[8];
    #pragma unroll
    for (int k = 0; k < 8; ++k) v[k] = bf2f(sl[k]);

    int j0 = rowptr[n], j1 = rowptr[n + 1];
    int j = j0;
    for (; j + 7 < j1; j += 8) {
        int s0 = csr[j],     s1 = csr[j + 1], s2 = csr[j + 2], s3 = csr[j + 3];
        int s4 = csr[j + 4], s5 = csr[j + 5], s6 = csr[j + 6], s7 = csr[j + 7];
        u16x8 g0 = h18[(size_t)s0 * 8 + li];
        u16x8 g1 = h18[(size_t)s1 * 8 + li];
        u16x8 g2 = h18[(size_t)s2 * 8 + li];
        u16x8 g3 = h18[(size_t)s3 * 8 + li];
        u16x8 g4 = h18[(size_t)s4 * 8 + li];
        u16x8 g5 = h18[(size_t)s5 * 8 + li];
        u16x8 g6 = h18[(size_t)s6 * 8 + li];
        u16x8 g7 = h18[(size_t)s7 * 8 + li];
        #pragma unroll
        for (int k = 0; k < 8; ++k) {
            v[k] += bf2f(g0[k]) + bf2f(g1[k]) + bf2f(g2[k]) + bf2f(g3[k]);
            v[k] += bf2f(g4[k]) + bf2f(g5[k]) + bf2f(g6[k]) + bf2f(g7[k]);
        }
    }
    for (; j + 3 < j1; j += 4) {
        int s0 = csr[j], s1 = csr[j + 1], s2 = csr[j + 2], s3 = csr[j + 3];
        u16x8 g0 = h18[(size_t)s0 * 8 + li];
        u16x8 g1 = h18[(size_t)s1 * 8 + li];
        u16x8 g2 = h18[(size_t)s2 * 8 + li];
        u16x8 g3 = h18[(size_t)s3 * 8 + li];
        #pragma unroll
        for (int k = 0; k < 8; ++k)
            v[k] += bf2f(g0[k]) + bf2f(g1[k]) + bf2f(g2[k]) + bf2f(g3[k]);
    }
    for (; j < j1; ++j) {
        u16x8 g = h18[(size_t)csr[j] * 8 + li];
        #pragma unroll
        for (int k = 0; k < 8; ++k) v[k] += bf2f(g[k]);
    }

    // bias + ReLU (feats f = li*8 + k)
    const float4 ba = *(const float4*)&b1[li * 8];
    const float4 bb = *(const float4*)&b1[li * 8 + 4];
    v[0] = fmaxf(di * v[0] + ba.x, 0.f); v[1] = fmaxf(di * v[1] + ba.y, 0.f);
    v[2] = fmaxf(di * v[2] + ba.z, 0.f); v[3] = fmaxf(di * v[3] + ba.w, 0.f);
    v[4] = fmaxf(di * v[4] + bb.x, 0.f); v[5] = fmaxf(di * v[5] + bb.y, 0.f);
    v[6] = fmaxf(di * v[6] + bb.z, 0.f); v[7] = fmaxf(di * v[7] + bb.w, 0.f);

    // W2 rows li*8 .. li*8+7 (each row = 2 floats): 4 float4 loads
    const float4* W24 = (const float4*)W2;
    float r0 = 0.f, r1 = 0.f;
    #pragma unroll
    for (int k = 0; k < 4; ++k) {
        float4 wq = W24[li * 4 + k];         // rows li*8+2k (x,y), li*8+2k+1 (z,w)
        r0 += v[2 * k] * wq.x + v[2 * k + 1] * wq.z;
        r1 += v[2 * k] * wq.y + v[2 * k + 1] * wq.w;
    }
    #pragma unroll
    for (int off = 1; off < 8; off <<= 1) {
        r0 += __shfl_xor(r0, off);
        r1 += __shfl_xor(r1, off);
    }
    if (li == 0) *(float2*)&h2[(size_t)n * EMB] = make_float2(r0 * di, r1 * di);  // h2' = dinv*h2
}

// ---------------------------------------------------------------------------
// Fused layer-2 CSR gather (pure sum of h2') + b2 + global mean pool
// + last-block finalize (replaces final_kernel launch).
__global__ __launch_bounds__(256) void agg2_pool_final_kernel(
        const int* __restrict__ rowptr, const int* __restrict__ csr,
        const float* __restrict__ h2,
        const float* __restrict__ dinv, const float* __restrict__ b2,
        const int* __restrict__ batch,
        float* __restrict__ sums, float* __restrict__ cntf, int* __restrict__ done,
        float* __restrict__ out, int N, int G) {
    int n = blockIdx.x * blockDim.x + threadIdx.x;
    int lane = threadIdx.x & 63;
    const float2* h2v = (const float2*)h2;
    float v0 = 0.f, v1 = 0.f, c = 0.f;
    int g = -1;
    if (n < N) {
        float di = dinv[n];
        float2 hs = h2v[n];
        v0 = hs.x; v1 = hs.y;
        int j0 = rowptr[n], j1 = rowptr[n + 1];
        int j = j0;
        for (; j + 7 < j1; j += 8) {
            int s0 = csr[j],     s1 = csr[j + 1], s2 = csr[j + 2], s3 = csr[j + 3];
            int s4 = csr[j + 4], s5 = csr[j + 5], s6 = csr[j + 6], s7 = csr[j + 7];
            float2 a = h2v[s0], b = h2v[s1], cc = h2v[s2], d = h2v[s3];
            float2 e = h2v[s4], f = h2v[s5], gg2 = h2v[s6], h = h2v[s7];
            v0 += a.x + b.x + cc.x + d.x;
            v1 += a.y + b.y + cc.y + d.y;
            v0 += e.x + f.x + gg2.x + h.x;
            v1 += e.y + f.y + gg2.y + h.y;
        }
        for (; j + 3 < j1; j += 4) {
            int s0 = csr[j], s1 = csr[j + 1], s2 = csr[j + 2], s3 = csr[j + 3];
            float2 a = h2v[s0], b = h2v[s1], cc = h2v[s2], d = h2v[s3];
            v0 += a.x + b.x + cc.x + d.x;
            v1 += a.y + b.y + cc.y + d.y;
        }
        for (; j < j1; ++j) {
            float2 hv = h2v[csr[j]];
            v0 += hv.x; v1 += hv.y;
        }
        v0 = di * v0 + b2[0];
        v1 = di * v1 + b2[1];
        g = batch[n];
        c = 1.f;
    }
    #pragma unroll
    for (int off = 1; off < 64; off <<= 1) {
        int gg = __shfl_up(g, off);
        float t0 = __shfl_up(v0, off);
        float t1 = __shfl_up(v1, off);
        float tc = __shfl_up(c, off);
        if (lane >= off && gg == g) { v0 += t0; v1 += t1; c += tc; }
    }
    int gn = __shfl_down(g, 1);
    if (g >= 0 && (lane == 63 || gn != g)) {
        atomicAdd(&sums[g * EMB + 0], v0);
        atomicAdd(&sums[g * EMB + 1], v1);
        atomicAdd(&cntf[g], c);
    }

    // last-block finalize (device-scope done counter; no dispatch-order assumption)
    __shared__ int sdone;
    __threadfence();
    if (threadIdx.x == 0) sdone = atomicAdd(done, 1);
    __syncthreads();
    if (sdone == (int)gridDim.x - 1) {
        for (int i = threadIdx.x; i < G; i += 256) {
            float s0 = atomicAdd(&sums[i * EMB + 0], 0.f);   // coherent read
            float s1 = atomicAdd(&sums[i * EMB + 1], 0.f);
            float cc = fmaxf(atomicAdd(&cntf[i], 0.f), 1.0f);
            out[i * EMB + 0] = s0 / cc;
            out[i * EMB + 1] = s1 / cc;
        }
    }
}

// ---------------------------------------------------------------------------
extern "C" void kernel_launch(void* const* d_in, const int* in_sizes, int n_in,
                              void* d_out, int out_size, void* d_ws, size_t ws_size,
                              hipStream_t stream) {
    const float* x     = (const float*)d_in[0];
    const int*   ei    = (const int*)d_in[1];
    const int*   batch = (const int*)d_in[2];
    const float* W1    = (const float*)d_in[3];
    const float* b1    = (const float*)d_in[4];
    const float* W2    = (const float*)d_in[5];
    const float* b2    = (const float*)d_in[6];
    float* out = (float*)d_out;

    const int N = in_sizes[0] / FIN;   // 100000
    const int E = in_sizes[1] / 2;     // 1600000
    const int G = out_size / EMB;      // 512
    const int* src = ei;
    const int* dst = ei + E;

    const int NBK = (N + BKSZ - 1) / BKSZ;                    // 196 coarse buckets
    const int chunk = (((E + CGRID - 1) / CGRID) + 3) & ~3;   // x4 -> 16B-aligned slices

    // ---- workspace layout (16 B aligned chunks) ----
    char* p = (char*)d_ws;
    auto take = [&](size_t bytes) { char* r = p; p += (bytes + 15) & ~(size_t)15; return r; };
    int*      counts = (int*)take(sizeof(int) * NBK * CGRID);
    int*      btot   = (int*)take(sizeof(int) * NBK);
    unsigned* ebuf   = (unsigned*)take(sizeof(unsigned) * E);
    int*      csr    = (int*)take(sizeof(int) * E);
    int*      rowptr = (int*)take(sizeof(int) * (N + 1));
    float*    dinv   = (float*)take(sizeof(float) * N);
    unsigned short* h1b = (unsigned short*)take(sizeof(unsigned short) * (size_t)N * HID);
    float*    h2     = (float*)take(sizeof(float) * (size_t)N * EMB);
    float*    pool   = (float*)take(sizeof(float) * (3 * G + 4));  // sums|cntf|done
    __bf16*   Bh     = (__bf16*)take(sizeof(__bf16) * 4 * 8 * 64 * 8);  // 32 KB
    __bf16*   Bl     = (__bf16*)take(sizeof(__bf16) * 4 * 8 * 64 * 8);  // 32 KB
    float*    sums   = pool;
    float*    cntf   = pool + 2 * G;
    int*      done   = (int*)(pool + 3 * G);

    // 1. CSR build chain: one cooperative launch (hist -> scan -> scatter -> build)
    CoopArgs ca;
    ca.src = src; ca.dst = dst; ca.counts = counts; ca.btot = btot;
    ca.ebuf = ebuf; ca.csr = csr; ca.rowptr = rowptr; ca.dinv = dinv;
    ca.W1 = W1; ca.Bh = Bh; ca.Bl = Bl; ca.pool = pool;
    ca.E = E; ca.chunk = chunk; ca.NBK = NBK; ca.N = N; ca.G = G;
    void* kargs[] = { (void*)&ca };
    hipLaunchCooperativeKernel((void*)coop_chain_kernel, dim3(CGRID), dim3(256),
                               kargs, 0, stream);
    // 2. h1' = dinv * (x @ W1)  (MFMA, pre-packed B frags, bf16 out, row-major)
    gemm1_kernel<<<(N + 63) / 64, 256, 0, stream>>>(x, Bh, Bl, dinv, h1b, N);
    // 3. fused agg1 + relu + W2 -> h2' = dinv*h2  (8 nodes/wave, 16 B/lane)
    agg1_layer2_kernel<<<(int)(((long)N * 8 + 255) / 256), 256, 0, stream>>>(
        rowptr, csr, h1b, dinv, b1, W2, h2, N);
    // 4. fused agg2 + pool + last-block finalize
    agg2_pool_final_kernel<<<(N + 255) / 256, 256, 0, stream>>>(
        rowptr, csr, h2, dinv, b2, batch, sums, cntf, done, out, N, G);
}

// Round 4
// 368.937 us; speedup vs baseline: 1.8269x; 1.8269x over previous
//
#include <hip/hip_runtime.h>
#include <hip/hip_bf16.h>

#define FIN 256
#define HID 64
#define EMB 2
#define BKB 9            // bucket = dst >> 9 (512 nodes per bucket)
#define BKSZ 512
#define MAXBK 256        // supports N <= 131072
#define NBLK 256         // blocks for binning passes
#define WPREP 8          // extra blocks in bin_hist grid that pre-pack W1

typedef __bf16 bf16x8 __attribute__((ext_vector_type(8)));
typedef float  f32x16 __attribute__((ext_vector_type(16)));
typedef unsigned short u16x8 __attribute__((ext_vector_type(8)));

// ---- bf16 helpers (RNE) ----
static __device__ __forceinline__ unsigned short f2bf(float f) {
    union { float f; unsigned int u; } v; v.f = f;
    unsigned int u = v.u;
    unsigned int r = (u + 0x7fffu + ((u >> 16) & 1u)) >> 16;
    return (unsigned short)r;
}
static __device__ __forceinline__ float bf2f(unsigned short h) {
    union { unsigned int u; float f; } v; v.u = ((unsigned int)h) << 16;
    return v.f;
}

// ---------------------------------------------------------------------------
// Pass A1: per-block histogram of coarse buckets + W1 pre-pack blocks.
__global__ __launch_bounds__(256) void bin_hist_kernel(
        const int* __restrict__ dst, int* __restrict__ counts,
        const float* __restrict__ W, __bf16* __restrict__ Bh, __bf16* __restrict__ Bl,
        int E, int chunk, int NBK) {
    if (blockIdx.x >= NBLK) {
        int t = (blockIdx.x - NBLK) * 256 + threadIdx.x;   // 0..2047
        int ch = t >> 9, g = (t >> 6) & 7, m = t & 63;
        int kbase = ch * 64 + (g & 3) * 16 + ((m >> 5) << 3);
        int n = ((g >> 2) << 5) + (m & 31);
        bf16x8 hi, lo;
        #pragma unroll
        for (int q = 0; q < 8; ++q) {
            float w = W[(size_t)(kbase + q) * HID + n];
            __bf16 h = (__bf16)w;
            hi[q] = h; lo[q] = (__bf16)(w - (float)h);
        }
        *(bf16x8*)&Bh[(size_t)t * 8] = hi;
        *(bf16x8*)&Bl[(size_t)t * 8] = lo;
        return;
    }
    __shared__ int hist[MAXBK];
    int tid = threadIdx.x;
    for (int b = tid; b < NBK; b += 256) hist[b] = 0;
    __syncthreads();
    int e0 = blockIdx.x * chunk, e1 = min(e0 + chunk, E);
    if (e0 < e1) {
        const int4* d4 = (const int4*)(dst + e0);
        int nv = (e1 - e0) >> 2;
        for (int i = tid; i < nv; i += 256) {
            int4 v = d4[i];
            atomicAdd(&hist[v.x >> BKB], 1);
            atomicAdd(&hist[v.y >> BKB], 1);
            atomicAdd(&hist[v.z >> BKB], 1);
            atomicAdd(&hist[v.w >> BKB], 1);
        }
        for (int i = e0 + (nv << 2) + tid; i < e1; i += 256)
            atomicAdd(&hist[dst[i] >> BKB], 1);
    }
    __syncthreads();
    for (int b = tid; b < NBK; b += 256) counts[b * NBLK + blockIdx.x] = hist[b];
}

// Scan 1/2: per-bucket exclusive scan of its 256 per-block counts.
__global__ __launch_bounds__(256) void scan_local_kernel(
        int* __restrict__ counts, int* __restrict__ btot) {
    __shared__ int s[256];
    const int b = blockIdx.x, tid = threadIdx.x;
    int v = counts[b * NBLK + tid];
    s[tid] = v;
    __syncthreads();
    for (int off = 1; off < 256; off <<= 1) {
        int t = (tid >= off) ? s[tid - off] : 0;
        __syncthreads();
        s[tid] += t;
        __syncthreads();
    }
    counts[b * NBLK + tid] = s[tid] - v;   // exclusive within bucket
    if (tid == 255) btot[b] = s[255];
}

// Scan 2/2: single block scans bucket totals + zero pool accumulators.
__global__ __launch_bounds__(256) void scan_tot_kernel(
        const int* __restrict__ btot, int* __restrict__ bucketBase,
        float* __restrict__ pool, int NBK, int nzero) {
    __shared__ int s[256];
    const int tid = threadIdx.x;
    int v = (tid < NBK) ? btot[tid] : 0;
    s[tid] = v;
    __syncthreads();
    for (int off = 1; off < 256; off <<= 1) {
        int t = (tid >= off) ? s[tid - off] : 0;
        __syncthreads();
        s[tid] += t;
        __syncthreads();
    }
    if (tid < NBK) bucketBase[tid] = s[tid] - v;
    if (tid == NBK - 1) bucketBase[NBK] = s[tid];
    for (int i = tid; i < nzero; i += 256) pool[i] = 0.f;
}

// Pass A2: scatter packed (src<<9 | dst&511) into per-(bucket,block) runs.
__global__ __launch_bounds__(256) void bin_scatter_kernel(
        const int* __restrict__ src, const int* __restrict__ dst,
        const int* __restrict__ counts, const int* __restrict__ bucketBase,
        unsigned* __restrict__ ebuf, int E, int chunk, int NBK) {
    __shared__ int cur[MAXBK];
    int tid = threadIdx.x;
    for (int b = tid; b < NBK; b += 256)
        cur[b] = bucketBase[b] + counts[b * NBLK + blockIdx.x];
    __syncthreads();
    int e0 = blockIdx.x * chunk, e1 = min(e0 + chunk, E);
    if (e0 >= e1) return;
    const int4* s4 = (const int4*)(src + e0);
    const int4* d4 = (const int4*)(dst + e0);
    int nv = (e1 - e0) >> 2;
    for (int i = tid; i < nv; i += 256) {
        int4 sv = s4[i], dv = d4[i];
        int b0 = dv.x >> BKB;
        int p0 = atomicAdd(&cur[b0], 1);
        ebuf[p0] = ((unsigned)sv.x << BKB) | (unsigned)(dv.x & (BKSZ - 1));
        int b1 = dv.y >> BKB;
        int p1 = atomicAdd(&cur[b1], 1);
        ebuf[p1] = ((unsigned)sv.y << BKB) | (unsigned)(dv.y & (BKSZ - 1));
        int b2 = dv.z >> BKB;
        int p2 = atomicAdd(&cur[b2], 1);
        ebuf[p2] = ((unsigned)sv.z << BKB) | (unsigned)(dv.z & (BKSZ - 1));
        int b3 = dv.w >> BKB;
        int p3 = atomicAdd(&cur[b3], 1);
        ebuf[p3] = ((unsigned)sv.w << BKB) | (unsigned)(dv.w & (BKSZ - 1));
    }
    for (int i = e0 + (nv << 2) + tid; i < e1; i += 256) {
        int s = src[i], d = dst[i];
        int b = d >> BKB;
        int pos = atomicAdd(&cur[b], 1);
        ebuf[pos] = ((unsigned)s << BKB) | (unsigned)(d & (BKSZ - 1));
    }
}

// Pass B: one block per bucket -> degree/dinv/rowptr + bucket-local CSR scatter
__global__ __launch_bounds__(256) void build_kernel(
        const unsigned* __restrict__ ebuf, const int* __restrict__ bucketBase,
        int* __restrict__ rowptr, float* __restrict__ dinv, int* __restrict__ csr,
        int N, int E) {
    __shared__ int hist[BKSZ];
    __shared__ int scanb[256];
    __shared__ int cur[BKSZ];
    const int b = blockIdx.x, tid = threadIdx.x;
    const int r0 = bucketBase[b];
    const int r1 = bucketBase[b + 1];
    const int nb0 = b * BKSZ;

    hist[tid] = 0; hist[tid + 256] = 0;
    __syncthreads();
    for (int i = r0 + tid; i < r1; i += 256)
        atomicAdd(&hist[ebuf[i] & (BKSZ - 1u)], 1);
    __syncthreads();

    int h0 = hist[2 * tid], h1 = hist[2 * tid + 1];
    if (nb0 + 2 * tid < N)     dinv[nb0 + 2 * tid]     = rsqrtf((float)h0 + 1.f);
    if (nb0 + 2 * tid + 1 < N) dinv[nb0 + 2 * tid + 1] = rsqrtf((float)h1 + 1.f);
    scanb[tid] = h0 + h1;
    __syncthreads();
    for (int off = 1; off < 256; off <<= 1) {
        int t = (tid >= off) ? scanb[tid - off] : 0;
        __syncthreads();
        scanb[tid] += t;
        __syncthreads();
    }
    int base0 = scanb[tid] - (h0 + h1);
    int o0 = base0, o1 = base0 + h0;
    cur[2 * tid] = o0; cur[2 * tid + 1] = o1;
    if (nb0 + 2 * tid < N)     rowptr[nb0 + 2 * tid]     = r0 + o0;
    if (nb0 + 2 * tid + 1 < N) rowptr[nb0 + 2 * tid + 1] = r0 + o1;
    if (nb0 + BKSZ >= N && tid == 0) rowptr[N] = E;
    __syncthreads();
    for (int i = r0 + tid; i < r1; i += 256) {
        unsigned u = ebuf[i];
        int loc = (int)(u & (BKSZ - 1u));
        int p = atomicAdd(&cur[loc], 1);
        csr[r0 + p] = (int)(u >> BKB);
    }
}

// ---------------------------------------------------------------------------
// h1' = dinv * (x @ W1) via MFMA. MEASUREMENT: internal x2 repeat (idempotent;
// opaque zero offset per rep blocks CSE/DSE so each rep does full work).
__global__ __launch_bounds__(256) void gemm1_kernel(
        const float* __restrict__ x,
        const __bf16* __restrict__ Bh, const __bf16* __restrict__ Bl,
        const float* __restrict__ dinv, unsigned short* __restrict__ h1b, int N) {
    __shared__ __align__(16) __bf16 A_hi[2 * 4 * 64 * 8];
    __shared__ __align__(16) __bf16 A_lo[2 * 4 * 64 * 8];

    const int tid = threadIdx.x;
    const int base = blockIdx.x * 64;
    const int w = tid >> 6;
    const int l = tid & 63;
    const int mg = w >> 1, ng = w & 1;

    const int r  = tid & 63;
    const int ks = tid >> 6;
    const int rl = r & 31, rh = r >> 5;

    int zro = 0;
    #pragma unroll 1
    for (int rep = 0; rep < 2; ++rep) {
        asm volatile("" : "+v"(zro));             // opaque 0: defeats CSE/DSE
        const float* xr = x + zro;
        const float* dvr = dinv + zro;
        unsigned short* h1r = h1b + zro;
        const bf16x8* Bh8 = (const bf16x8*)Bh + zro;
        const bf16x8* Bl8 = (const bf16x8*)Bl + zro;

        f32x16 acc = {};
        for (int ch = 0; ch < 4; ++ch) {
            const int ck0 = ch * 64;
            __syncthreads();
            {
                int row = base + r;
                float f[16];
                if (row < N) {
                    const float* xp = &xr[(size_t)row * FIN + ck0 + ks * 16];
                    float4 v0 = *(const float4*)(xp + 0);
                    float4 v1 = *(const float4*)(xp + 4);
                    float4 v2 = *(const float4*)(xp + 8);
                    float4 v3 = *(const float4*)(xp + 12);
                    f[0]=v0.x; f[1]=v0.y; f[2]=v0.z; f[3]=v0.w;
                    f[4]=v1.x; f[5]=v1.y; f[6]=v1.z; f[7]=v1.w;
                    f[8]=v2.x; f[9]=v2.y; f[10]=v2.z; f[11]=v2.w;
                    f[12]=v3.x; f[13]=v3.y; f[14]=v3.z; f[15]=v3.w;
                } else {
                    #pragma unroll
                    for (int q = 0; q < 16; ++q) f[q] = 0.f;
                }
                bf16x8 ha, hb, la, lb;
                #pragma unroll
                for (int q = 0; q < 8; ++q) {
                    __bf16 h0 = (__bf16)f[q];
                    ha[q] = h0; la[q] = (__bf16)(f[q] - (float)h0);
                    __bf16 h1v = (__bf16)f[q + 8];
                    hb[q] = h1v; lb[q] = (__bf16)(f[q + 8] - (float)h1v);
                }
                int ra = ((rh * 4 + ks) * 64 + rl) * 8;
                int rb = ((rh * 4 + ks) * 64 + 32 + rl) * 8;
                *(bf16x8*)&A_hi[ra] = ha; *(bf16x8*)&A_hi[rb] = hb;
                *(bf16x8*)&A_lo[ra] = la; *(bf16x8*)&A_lo[rb] = lb;
            }
            __syncthreads();

            #pragma unroll
            for (int s = 0; s < 4; ++s) {
                bf16x8 a_h = *(const bf16x8*)&A_hi[((mg * 4 + s) * 64 + l) * 8];
                bf16x8 a_l = *(const bf16x8*)&A_lo[((mg * 4 + s) * 64 + l) * 8];
                int bv = (ch * 8 + ng * 4 + s) * 64 + l;
                bf16x8 b_h = Bh8[bv];
                bf16x8 b_l = Bl8[bv];
                acc = __builtin_amdgcn_mfma_f32_32x32x16_bf16(a_h, b_h, acc, 0, 0, 0);
                acc = __builtin_amdgcn_mfma_f32_32x32x16_bf16(a_h, b_l, acc, 0, 0, 0);
                acc = __builtin_amdgcn_mfma_f32_32x32x16_bf16(a_l, b_h, acc, 0, 0, 0);
            }
        }

        const int col = l & 31;
        const int rbase = 4 * (l >> 5);
        #pragma unroll
        for (int reg = 0; reg < 16; ++reg) {
            int row = (reg & 3) + 8 * (reg >> 2) + rbase;
            int node = base + mg * 32 + row;
            if (node < N)
                h1r[(size_t)node * HID + ng * 32 + col] = f2bf(acc[reg] * dvr[node]);
        }
    }
}

// ---------------------------------------------------------------------------
// Fused layer-1 CSR gather + b1 + ReLU + (64->2). MEASUREMENT: internal x2.
__global__ __launch_bounds__(256) void agg1_layer2_kernel(
        const int* __restrict__ rowptr, const int* __restrict__ csr,
        const unsigned short* __restrict__ h1b,
        const float* __restrict__ dinv, const float* __restrict__ b1,
        const float* __restrict__ W2, float* __restrict__ h2, int N) {
    long t = (long)blockIdx.x * blockDim.x + threadIdx.x;
    int n = (int)(t >> 3);
    int li = threadIdx.x & 7;
    if (n >= N) return;

    int zro = 0;
    #pragma unroll 1
    for (int rep = 0; rep < 2; ++rep) {
        asm volatile("" : "+v"(zro));             // opaque 0: defeats CSE/DSE
        const u16x8* h18 = (const u16x8*)h1b + zro;
        const int* csr_r = csr + zro;
        float* h2r = h2 + zro;

        float di = dinv[n];
        u16x8 sl = h18[(size_t)n * 8 + li];      // self term (h1' pre-scaled)
        float v[8];
        #pragma unroll
        for (int k = 0; k < 8; ++k) v[k] = bf2f(sl[k]);

        int j0 = rowptr[n], j1 = rowptr[n + 1];
        int j = j0;
        for (; j + 7 < j1; j += 8) {
            int s0 = csr_r[j],     s1 = csr_r[j + 1], s2 = csr_r[j + 2], s3 = csr_r[j + 3];
            int s4 = csr_r[j + 4], s5 = csr_r[j + 5], s6 = csr_r[j + 6], s7 = csr_r[j + 7];
            u16x8 g0 = h18[(size_t)s0 * 8 + li];
            u16x8 g1 = h18[(size_t)s1 * 8 + li];
            u16x8 g2 = h18[(size_t)s2 * 8 + li];
            u16x8 g3 = h18[(size_t)s3 * 8 + li];
            u16x8 g4 = h18[(size_t)s4 * 8 + li];
            u16x8 g5 = h18[(size_t)s5 * 8 + li];
            u16x8 g6 = h18[(size_t)s6 * 8 + li];
            u16x8 g7 = h18[(size_t)s7 * 8 + li];
            #pragma unroll
            for (int k = 0; k < 8; ++k) {
                v[k] += bf2f(g0[k]) + bf2f(g1[k]) + bf2f(g2[k]) + bf2f(g3[k]);
                v[k] += bf2f(g4[k]) + bf2f(g5[k]) + bf2f(g6[k]) + bf2f(g7[k]);
            }
        }
        for (; j + 3 < j1; j += 4) {
            int s0 = csr_r[j], s1 = csr_r[j + 1], s2 = csr_r[j + 2], s3 = csr_r[j + 3];
            u16x8 g0 = h18[(size_t)s0 * 8 + li];
            u16x8 g1 = h18[(size_t)s1 * 8 + li];
            u16x8 g2 = h18[(size_t)s2 * 8 + li];
            u16x8 g3 = h18[(size_t)s3 * 8 + li];
            #pragma unroll
            for (int k = 0; k < 8; ++k)
                v[k] += bf2f(g0[k]) + bf2f(g1[k]) + bf2f(g2[k]) + bf2f(g3[k]);
        }
        for (; j < j1; ++j) {
            u16x8 g = h18[(size_t)csr_r[j] * 8 + li];
            #pragma unroll
            for (int k = 0; k < 8; ++k) v[k] += bf2f(g[k]);
        }

        const float4 ba = *(const float4*)&b1[li * 8];
        const float4 bb = *(const float4*)&b1[li * 8 + 4];
        v[0] = fmaxf(di * v[0] + ba.x, 0.f); v[1] = fmaxf(di * v[1] + ba.y, 0.f);
        v[2] = fmaxf(di * v[2] + ba.z, 0.f); v[3] = fmaxf(di * v[3] + ba.w, 0.f);
        v[4] = fmaxf(di * v[4] + bb.x, 0.f); v[5] = fmaxf(di * v[5] + bb.y, 0.f);
        v[6] = fmaxf(di * v[6] + bb.z, 0.f); v[7] = fmaxf(di * v[7] + bb.w, 0.f);

        const float4* W24 = (const float4*)W2;
        float r0 = 0.f, r1 = 0.f;
        #pragma unroll
        for (int k = 0; k < 4; ++k) {
            float4 wq = W24[li * 4 + k];
            r0 += v[2 * k] * wq.x + v[2 * k + 1] * wq.z;
            r1 += v[2 * k] * wq.y + v[2 * k + 1] * wq.w;
        }
        #pragma unroll
        for (int off = 1; off < 8; off <<= 1) {
            r0 += __shfl_xor(r0, off);
            r1 += __shfl_xor(r1, off);
        }
        if (li == 0) *(float2*)&h2r[(size_t)n * EMB] = make_float2(r0 * di, r1 * di);
    }
}

// ---------------------------------------------------------------------------
// Fused layer-2 CSR gather + b2 + global mean pool. MEASUREMENT: internal x2,
// rep 0 -> scratch accumulators, rep 1 -> real.
__global__ __launch_bounds__(256) void agg2_pool_kernel(
        const int* __restrict__ rowptr, const int* __restrict__ csr,
        const float* __restrict__ h2,
        const float* __restrict__ dinv, const float* __restrict__ b2,
        const int* __restrict__ batch,
        float* __restrict__ sums, float* __restrict__ cntf,
        float* __restrict__ sums2, float* __restrict__ cntf2, int N) {
    int n = blockIdx.x * blockDim.x + threadIdx.x;
    int lane = threadIdx.x & 63;

    int zro = 0;
    #pragma unroll 1
    for (int rep = 0; rep < 2; ++rep) {
        asm volatile("" : "+v"(zro));             // opaque 0: defeats CSE
        const float2* h2v = (const float2*)h2 + zro;
        const int* csr_r = csr + zro;
        float* S = rep ? sums : sums2;
        float* C = rep ? cntf : cntf2;

        float v0 = 0.f, v1 = 0.f, c = 0.f;
        int g = -1;
        if (n < N) {
            float di = dinv[n];
            float2 hs = h2v[n];
            v0 = hs.x; v1 = hs.y;
            int j0 = rowptr[n], j1 = rowptr[n + 1];
            int j = j0;
            for (; j + 7 < j1; j += 8) {
                int s0 = csr_r[j],     s1 = csr_r[j + 1], s2 = csr_r[j + 2], s3 = csr_r[j + 3];
                int s4 = csr_r[j + 4], s5 = csr_r[j + 5], s6 = csr_r[j + 6], s7 = csr_r[j + 7];
                float2 a = h2v[s0], b = h2v[s1], cc = h2v[s2], d = h2v[s3];
                float2 e = h2v[s4], f = h2v[s5], gg2 = h2v[s6], h = h2v[s7];
                v0 += a.x + b.x + cc.x + d.x;
                v1 += a.y + b.y + cc.y + d.y;
                v0 += e.x + f.x + gg2.x + h.x;
                v1 += e.y + f.y + gg2.y + h.y;
            }
            for (; j + 3 < j1; j += 4) {
                int s0 = csr_r[j], s1 = csr_r[j + 1], s2 = csr_r[j + 2], s3 = csr_r[j + 3];
                float2 a = h2v[s0], b = h2v[s1], cc = h2v[s2], d = h2v[s3];
                v0 += a.x + b.x + cc.x + d.x;
                v1 += a.y + b.y + cc.y + d.y;
            }
            for (; j < j1; ++j) {
                float2 hv = h2v[csr_r[j]];
                v0 += hv.x; v1 += hv.y;
            }
            v0 = di * v0 + b2[0];
            v1 = di * v1 + b2[1];
            g = batch[n];
            c = 1.f;
        }
        #pragma unroll
        for (int off = 1; off < 64; off <<= 1) {
            int gg = __shfl_up(g, off);
            float t0 = __shfl_up(v0, off);
            float t1 = __shfl_up(v1, off);
            float tc = __shfl_up(c, off);
            if (lane >= off && gg == g) { v0 += t0; v1 += t1; c += tc; }
        }
        int gn = __shfl_down(g, 1);
        if (g >= 0 && (lane == 63 || gn != g)) {
            atomicAdd(&S[g * EMB + 0], v0);
            atomicAdd(&S[g * EMB + 1], v1);
            atomicAdd(&C[g], c);
        }
    }
}

__global__ void final_kernel(const float* __restrict__ sums, const float* __restrict__ cntf,
                             float* __restrict__ out, int G) {
    int g = blockIdx.x * blockDim.x + threadIdx.x;
    if (g >= G) return;
    float c = fmaxf(cntf[g], 1.0f);
    out[g * EMB + 0] = sums[g * EMB + 0] / c;
    out[g * EMB + 1] = sums[g * EMB + 1] / c;
}

// ---------------------------------------------------------------------------
extern "C" void kernel_launch(void* const* d_in, const int* in_sizes, int n_in,
                              void* d_out, int out_size, void* d_ws, size_t ws_size,
                              hipStream_t stream) {
    const float* x     = (const float*)d_in[0];
    const int*   ei    = (const int*)d_in[1];
    const int*   batch = (const int*)d_in[2];
    const float* W1    = (const float*)d_in[3];
    const float* b1    = (const float*)d_in[4];
    const float* W2    = (const float*)d_in[5];
    const float* b2    = (const float*)d_in[6];
    float* out = (float*)d_out;

    const int N = in_sizes[0] / FIN;   // 100000
    const int E = in_sizes[1] / 2;     // 1600000
    const int G = out_size / EMB;      // 512
    const int* src = ei;
    const int* dst = ei + E;

    const int NBK = (N + BKSZ - 1) / BKSZ;                    // 196 coarse buckets
    const int chunk = (((E + NBLK - 1) / NBLK) + 3) & ~3;     // x4 -> 16B-aligned slices

    // ---- workspace layout (16 B aligned chunks) ----
    char* p = (char*)d_ws;
    auto take = [&](size_t bytes) { char* r = p; p += (bytes + 15) & ~(size_t)15; return r; };
    int*      counts = (int*)take(sizeof(int) * NBK * NBLK);
    int*      btot   = (int*)take(sizeof(int) * NBK);
    int*      bucketBase = (int*)take(sizeof(int) * (NBK + 1));
    unsigned* ebuf   = (unsigned*)take(sizeof(unsigned) * E);
    int*      csr    = (int*)take(sizeof(int) * E);
    int*      rowptr = (int*)take(sizeof(int) * (N + 1));
    float*    dinv   = (float*)take(sizeof(float) * N);
    unsigned short* h1b = (unsigned short*)take(sizeof(unsigned short) * (size_t)N * HID);
    float*    h2     = (float*)take(sizeof(float) * (size_t)N * EMB);
    float*    pool   = (float*)take(sizeof(float) * 6 * G);   // sums|cntf|sums2|cntf2
    __bf16*   Bh     = (__bf16*)take(sizeof(__bf16) * 4 * 8 * 64 * 8);  // 32 KB
    __bf16*   Bl     = (__bf16*)take(sizeof(__bf16) * 4 * 8 * 64 * 8);  // 32 KB
    float*    sums   = pool;
    float*    cntf   = pool + 2 * G;
    float*    sums2  = pool + 3 * G;
    float*    cntf2  = pool + 5 * G;

    // 1. CSR build: hist(+W1 pre-pack) -> 2-level bucket scan (+zero pool)
    //    -> scatter -> build
    bin_hist_kernel<<<NBLK + WPREP, 256, 0, stream>>>(dst, counts, W1, Bh, Bl, E, chunk, NBK);
    scan_local_kernel<<<NBK, 256, 0, stream>>>(counts, btot);
    scan_tot_kernel<<<1, 256, 0, stream>>>(btot, bucketBase, pool, NBK, 6 * G);
    bin_scatter_kernel<<<NBLK, 256, 0, stream>>>(src, dst, counts, bucketBase, ebuf, E, chunk, NBK);
    build_kernel<<<NBK, 256, 0, stream>>>(ebuf, bucketBase, rowptr, dinv, csr, N, E);
    // 2. h1' = dinv * (x @ W1)  (x2 internal repeat for measurement)
    gemm1_kernel<<<(N + 63) / 64, 256, 0, stream>>>(x, Bh, Bl, dinv, h1b, N);
    // 3. fused agg1 + relu + W2 (x2 internal repeat for measurement)
    agg1_layer2_kernel<<<(int)(((long)N * 8 + 255) / 256), 256, 0, stream>>>(
        rowptr, csr, h1b, dinv, b1, W2, h2, N);
    // 4. fused agg2 + pool (x2: scratch then real), then finalize
    agg2_pool_kernel<<<(N + 255) / 256, 256, 0, stream>>>(
        rowptr, csr, h2, dinv, b2, batch, sums, cntf, sums2, cntf2, N);
    final_kernel<<<(G + 255) / 256, 256, 0, stream>>>(sums, cntf, out, G);
}

// Round 7
// 310.097 us; speedup vs baseline: 2.1736x; 1.1897x over previous
//
#include <hip/hip_runtime.h>
#include <hip/hip_bf16.h>

#define FIN 256
#define HID 64
#define EMB 2
#define BKB 9            // bucket = dst >> 9 (512 nodes per bucket)
#define BKSZ 512
#define MAXBK 256        // supports N <= 131072
#define NBLK 256         // blocks for binning passes
#define WPREP 8          // extra blocks in bin_hist grid that pre-pack W1

typedef __bf16 bf16x8 __attribute__((ext_vector_type(8)));
typedef float  f32x16 __attribute__((ext_vector_type(16)));
typedef unsigned short u16x8 __attribute__((ext_vector_type(8)));

// ---- bf16 helpers (RNE) ----
static __device__ __forceinline__ unsigned short f2bf(float f) {
    union { float f; unsigned int u; } v; v.f = f;
    unsigned int u = v.u;
    unsigned int r = (u + 0x7fffu + ((u >> 16) & 1u)) >> 16;
    return (unsigned short)r;
}
static __device__ __forceinline__ float bf2f(unsigned short h) {
    union { unsigned int u; float f; } v; v.u = ((unsigned int)h) << 16;
    return v.f;
}

// ---------------------------------------------------------------------------
// Pass A1: per-block histogram of coarse buckets + W1 pre-pack blocks.
// Block 0 additionally zeroes the agg2 done-counter (stream-ordered visibility).
__global__ __launch_bounds__(256) void bin_hist_kernel(
        const int* __restrict__ dst, int* __restrict__ counts,
        const float* __restrict__ W, __bf16* __restrict__ Bh, __bf16* __restrict__ Bl,
        int* __restrict__ done, int E, int chunk, int NBK) {
    if (blockIdx.x >= NBLK) {
        int t = (blockIdx.x - NBLK) * 256 + threadIdx.x;   // 0..2047
        int ch = t >> 9, g = (t >> 6) & 7, m = t & 63;
        int kbase = ch * 64 + (g & 3) * 16 + ((m >> 5) << 3);
        int n = ((g >> 2) << 5) + (m & 31);
        bf16x8 hi, lo;
        #pragma unroll
        for (int q = 0; q < 8; ++q) {
            float w = W[(size_t)(kbase + q) * HID + n];
            __bf16 h = (__bf16)w;
            hi[q] = h; lo[q] = (__bf16)(w - (float)h);
        }
        *(bf16x8*)&Bh[(size_t)t * 8] = hi;
        *(bf16x8*)&Bl[(size_t)t * 8] = lo;
        return;
    }
    __shared__ int hist[MAXBK];
    int tid = threadIdx.x;
    if (blockIdx.x == 0 && tid == 0) done[0] = 0;
    for (int b = tid; b < NBK; b += 256) hist[b] = 0;
    __syncthreads();
    int e0 = blockIdx.x * chunk, e1 = min(e0 + chunk, E);
    if (e0 < e1) {
        const int4* d4 = (const int4*)(dst + e0);
        int nv = (e1 - e0) >> 2;
        for (int i = tid; i < nv; i += 256) {
            int4 v = d4[i];
            atomicAdd(&hist[v.x >> BKB], 1);
            atomicAdd(&hist[v.y >> BKB], 1);
            atomicAdd(&hist[v.z >> BKB], 1);
            atomicAdd(&hist[v.w >> BKB], 1);
        }
        for (int i = e0 + (nv << 2) + tid; i < e1; i += 256)
            atomicAdd(&hist[dst[i] >> BKB], 1);
    }
    __syncthreads();
    for (int b = tid; b < NBK; b += 256) counts[b * NBLK + blockIdx.x] = hist[b];
}

// Scan 1/2: per-bucket exclusive scan of its 256 per-block counts.
__global__ __launch_bounds__(256) void scan_local_kernel(
        int* __restrict__ counts, int* __restrict__ btot) {
    __shared__ int s[256];
    const int b = blockIdx.x, tid = threadIdx.x;
    int v = counts[b * NBLK + tid];
    s[tid] = v;
    __syncthreads();
    for (int off = 1; off < 256; off <<= 1) {
        int t = (tid >= off) ? s[tid - off] : 0;
        __syncthreads();
        s[tid] += t;
        __syncthreads();
    }
    counts[b * NBLK + tid] = s[tid] - v;   // exclusive within bucket
    if (tid == 255) btot[b] = s[255];
}

// Scan 2/2: single block scans bucket totals + zero pool accumulators.
__global__ __launch_bounds__(256) void scan_tot_kernel(
        const int* __restrict__ btot, int* __restrict__ bucketBase,
        float* __restrict__ pool, int NBK, int nzero) {
    __shared__ int s[256];
    const int tid = threadIdx.x;
    int v = (tid < NBK) ? btot[tid] : 0;
    s[tid] = v;
    __syncthreads();
    for (int off = 1; off < 256; off <<= 1) {
        int t = (tid >= off) ? s[tid - off] : 0;
        __syncthreads();
        s[tid] += t;
        __syncthreads();
    }
    if (tid < NBK) bucketBase[tid] = s[tid] - v;
    if (tid == NBK - 1) bucketBase[NBK] = s[tid];
    for (int i = tid; i < nzero; i += 256) pool[i] = 0.f;
}

// Pass A2: scatter packed (src<<9 | dst&511) into per-(bucket,block) runs.
__global__ __launch_bounds__(256) void bin_scatter_kernel(
        const int* __restrict__ src, const int* __restrict__ dst,
        const int* __restrict__ counts, const int* __restrict__ bucketBase,
        unsigned* __restrict__ ebuf, int E, int chunk, int NBK) {
    __shared__ int cur[MAXBK];
    int tid = threadIdx.x;
    for (int b = tid; b < NBK; b += 256)
        cur[b] = bucketBase[b] + counts[b * NBLK + blockIdx.x];
    __syncthreads();
    int e0 = blockIdx.x * chunk, e1 = min(e0 + chunk, E);
    if (e0 >= e1) return;
    const int4* s4 = (const int4*)(src + e0);
    const int4* d4 = (const int4*)(dst + e0);
    int nv = (e1 - e0) >> 2;
    for (int i = tid; i < nv; i += 256) {
        int4 sv = s4[i], dv = d4[i];
        int b0 = dv.x >> BKB;
        int p0 = atomicAdd(&cur[b0], 1);
        ebuf[p0] = ((unsigned)sv.x << BKB) | (unsigned)(dv.x & (BKSZ - 1));
        int b1 = dv.y >> BKB;
        int p1 = atomicAdd(&cur[b1], 1);
        ebuf[p1] = ((unsigned)sv.y << BKB) | (unsigned)(dv.y & (BKSZ - 1));
        int b2 = dv.z >> BKB;
        int p2 = atomicAdd(&cur[b2], 1);
        ebuf[p2] = ((unsigned)sv.z << BKB) | (unsigned)(dv.z & (BKSZ - 1));
        int b3 = dv.w >> BKB;
        int p3 = atomicAdd(&cur[b3], 1);
        ebuf[p3] = ((unsigned)sv.w << BKB) | (unsigned)(dv.w & (BKSZ - 1));
    }
    for (int i = e0 + (nv << 2) + tid; i < e1; i += 256) {
        int s = src[i], d = dst[i];
        int b = d >> BKB;
        int pos = atomicAdd(&cur[b], 1);
        ebuf[pos] = ((unsigned)s << BKB) | (unsigned)(d & (BKSZ - 1));
    }
}

// Pass B: one block per bucket -> degree/dinv/rowptr + bucket-local CSR scatter
__global__ __launch_bounds__(256) void build_kernel(
        const unsigned* __restrict__ ebuf, const int* __restrict__ bucketBase,
        int* __restrict__ rowptr, float* __restrict__ dinv, int* __restrict__ csr,
        int N, int E) {
    __shared__ int hist[BKSZ];
    __shared__ int scanb[256];
    __shared__ int cur[BKSZ];
    const int b = blockIdx.x, tid = threadIdx.x;
    const int r0 = bucketBase[b];
    const int r1 = bucketBase[b + 1];
    const int nb0 = b * BKSZ;

    hist[tid] = 0; hist[tid + 256] = 0;
    __syncthreads();
    for (int i = r0 + tid; i < r1; i += 256)
        atomicAdd(&hist[ebuf[i] & (BKSZ - 1u)], 1);
    __syncthreads();

    int h0 = hist[2 * tid], h1 = hist[2 * tid + 1];
    if (nb0 + 2 * tid < N)     dinv[nb0 + 2 * tid]     = rsqrtf((float)h0 + 1.f);
    if (nb0 + 2 * tid + 1 < N) dinv[nb0 + 2 * tid + 1] = rsqrtf((float)h1 + 1.f);
    scanb[tid] = h0 + h1;
    __syncthreads();
    for (int off = 1; off < 256; off <<= 1) {
        int t = (tid >= off) ? scanb[tid - off] : 0;
        __syncthreads();
        scanb[tid] += t;
        __syncthreads();
    }
    int base0 = scanb[tid] - (h0 + h1);
    int o0 = base0, o1 = base0 + h0;
    cur[2 * tid] = o0; cur[2 * tid + 1] = o1;
    if (nb0 + 2 * tid < N)     rowptr[nb0 + 2 * tid]     = r0 + o0;
    if (nb0 + 2 * tid + 1 < N) rowptr[nb0 + 2 * tid + 1] = r0 + o1;
    if (nb0 + BKSZ >= N && tid == 0) rowptr[N] = E;
    __syncthreads();
    for (int i = r0 + tid; i < r1; i += 256) {
        unsigned u = ebuf[i];
        int loc = (int)(u & (BKSZ - 1u));
        int p = atomicAdd(&cur[loc], 1);
        csr[r0 + p] = (int)(u >> BKB);
    }
}

// ---------------------------------------------------------------------------
// h1' = dinv * (x @ W1) via MFMA (bf16 hi/lo split: xh*wh + xh*wl + xl*wh).
// Block = 64-node x 64-feat tile, 4 waves = four 32x32 quadrants. bf16 store.
__global__ __launch_bounds__(256) void gemm1_kernel(
        const float* __restrict__ x,
        const __bf16* __restrict__ Bh, const __bf16* __restrict__ Bl,
        const float* __restrict__ dinv, unsigned short* __restrict__ h1b, int N) {
    __shared__ __align__(16) __bf16 A_hi[2 * 4 * 64 * 8];
    __shared__ __align__(16) __bf16 A_lo[2 * 4 * 64 * 8];

    const int tid = threadIdx.x;
    const int base = blockIdx.x * 64;
    const int w = tid >> 6;
    const int l = tid & 63;
    const int mg = w >> 1, ng = w & 1;

    const bf16x8* Bh8 = (const bf16x8*)Bh;
    const bf16x8* Bl8 = (const bf16x8*)Bl;

    f32x16 acc = {};

    const int r  = tid & 63;
    const int ks = tid >> 6;
    const int rl = r & 31, rh = r >> 5;

    for (int ch = 0; ch < 4; ++ch) {
        const int ck0 = ch * 64;
        __syncthreads();
        {
            int row = base + r;
            float f[16];
            if (row < N) {
                const float* xp = &x[(size_t)row * FIN + ck0 + ks * 16];
                float4 v0 = *(const float4*)(xp + 0);
                float4 v1 = *(const float4*)(xp + 4);
                float4 v2 = *(const float4*)(xp + 8);
                float4 v3 = *(const float4*)(xp + 12);
                f[0]=v0.x; f[1]=v0.y; f[2]=v0.z; f[3]=v0.w;
                f[4]=v1.x; f[5]=v1.y; f[6]=v1.z; f[7]=v1.w;
                f[8]=v2.x; f[9]=v2.y; f[10]=v2.z; f[11]=v2.w;
                f[12]=v3.x; f[13]=v3.y; f[14]=v3.z; f[15]=v3.w;
            } else {
                #pragma unroll
                for (int q = 0; q < 16; ++q) f[q] = 0.f;
            }
            bf16x8 ha, hb, la, lb;
            #pragma unroll
            for (int q = 0; q < 8; ++q) {
                __bf16 h0 = (__bf16)f[q];
                ha[q] = h0; la[q] = (__bf16)(f[q] - (float)h0);
                __bf16 h1v = (__bf16)f[q + 8];
                hb[q] = h1v; lb[q] = (__bf16)(f[q + 8] - (float)h1v);
            }
            int ra = ((rh * 4 + ks) * 64 + rl) * 8;
            int rb = ((rh * 4 + ks) * 64 + 32 + rl) * 8;
            *(bf16x8*)&A_hi[ra] = ha; *(bf16x8*)&A_hi[rb] = hb;
            *(bf16x8*)&A_lo[ra] = la; *(bf16x8*)&A_lo[rb] = lb;
        }
        __syncthreads();

        #pragma unroll
        for (int s = 0; s < 4; ++s) {
            bf16x8 a_h = *(const bf16x8*)&A_hi[((mg * 4 + s) * 64 + l) * 8];
            bf16x8 a_l = *(const bf16x8*)&A_lo[((mg * 4 + s) * 64 + l) * 8];
            int bv = (ch * 8 + ng * 4 + s) * 64 + l;
            bf16x8 b_h = Bh8[bv];
            bf16x8 b_l = Bl8[bv];
            acc = __builtin_amdgcn_mfma_f32_32x32x16_bf16(a_h, b_h, acc, 0, 0, 0);
            acc = __builtin_amdgcn_mfma_f32_32x32x16_bf16(a_h, b_l, acc, 0, 0, 0);
            acc = __builtin_amdgcn_mfma_f32_32x32x16_bf16(a_l, b_h, acc, 0, 0, 0);
        }
    }

    const int col = l & 31;
    const int rbase = 4 * (l >> 5);
    #pragma unroll
    for (int reg = 0; reg < 16; ++reg) {
        int row = (reg & 3) + 8 * (reg >> 2) + rbase;
        int node = base + mg * 32 + row;
        if (node < N)
            h1b[(size_t)node * HID + ng * 32 + col] = f2bf(acc[reg] * dinv[node]);
    }
}

// ---------------------------------------------------------------------------
// Fused layer-1 CSR gather (pure sum of pre-scaled h1') + b1 + ReLU + (64->2).
// 8 nodes per wave: 8 lanes/node, lane = 8 feats (ushort8 = 16 B/lane gather).
__global__ __launch_bounds__(256) void agg1_layer2_kernel(
        const int* __restrict__ rowptr, const int* __restrict__ csr,
        const unsigned short* __restrict__ h1b,
        const float* __restrict__ dinv, const float* __restrict__ b1,
        const float* __restrict__ W2, float* __restrict__ h2, int N) {
    long t = (long)blockIdx.x * blockDim.x + threadIdx.x;
    int n = (int)(t >> 3);
    int li = threadIdx.x & 7;
    if (n >= N) return;
    const u16x8* h18 = (const u16x8*)h1b;    // row = 8 vectors x 8 feats

    float di = dinv[n];
    u16x8 sl = h18[(size_t)n * 8 + li];      // self term (h1' pre-scaled)
    float v[8];
    #pragma unroll
    for (int k = 0; k < 8; ++k) v[k] = bf2f(sl[k]);

    int j0 = rowptr[n], j1 = rowptr[n + 1];
    int j = j0;
    for (; j + 7 < j1; j += 8) {
        int s0 = csr[j],     s1 = csr[j + 1], s2 = csr[j + 2], s3 = csr[j + 3];
        int s4 = csr[j + 4], s5 = csr[j + 5], s6 = csr[j + 6], s7 = csr[j + 7];
        u16x8 g0 = h18[(size_t)s0 * 8 + li];
        u16x8 g1 = h18[(size_t)s1 * 8 + li];
        u16x8 g2 = h18[(size_t)s2 * 8 + li];
        u16x8 g3 = h18[(size_t)s3 * 8 + li];
        u16x8 g4 = h18[(size_t)s4 * 8 + li];
        u16x8 g5 = h18[(size_t)s5 * 8 + li];
        u16x8 g6 = h18[(size_t)s6 * 8 + li];
        u16x8 g7 = h18[(size_t)s7 * 8 + li];
        #pragma unroll
        for (int k = 0; k < 8; ++k) {
            v[k] += bf2f(g0[k]) + bf2f(g1[k]) + bf2f(g2[k]) + bf2f(g3[k]);
            v[k] += bf2f(g4[k]) + bf2f(g5[k]) + bf2f(g6[k]) + bf2f(g7[k]);
        }
    }
    for (; j + 3 < j1; j += 4) {
        int s0 = csr[j], s1 = csr[j + 1], s2 = csr[j + 2], s3 = csr[j + 3];
        u16x8 g0 = h18[(size_t)s0 * 8 + li];
        u16x8 g1 = h18[(size_t)s1 * 8 + li];
        u16x8 g2 = h18[(size_t)s2 * 8 + li];
        u16x8 g3 = h18[(size_t)s3 * 8 + li];
        #pragma unroll
        for (int k = 0; k < 8; ++k)
            v[k] += bf2f(g0[k]) + bf2f(g1[k]) + bf2f(g2[k]) + bf2f(g3[k]);
    }
    for (; j < j1; ++j) {
        u16x8 g = h18[(size_t)csr[j] * 8 + li];
        #pragma unroll
        for (int k = 0; k < 8; ++k) v[k] += bf2f(g[k]);
    }

    // bias + ReLU (feats f = li*8 + k)
    const float4 ba = *(const float4*)&b1[li * 8];
    const float4 bb = *(const float4*)&b1[li * 8 + 4];
    v[0] = fmaxf(di * v[0] + ba.x, 0.f); v[1] = fmaxf(di * v[1] + ba.y, 0.f);
    v[2] = fmaxf(di * v[2] + ba.z, 0.f); v[3] = fmaxf(di * v[3] + ba.w, 0.f);
    v[4] = fmaxf(di * v[4] + bb.x, 0.f); v[5] = fmaxf(di * v[5] + bb.y, 0.f);
    v[6] = fmaxf(di * v[6] + bb.z, 0.f); v[7] = fmaxf(di * v[7] + bb.w, 0.f);

    // W2 rows li*8 .. li*8+7 (each row = 2 floats): 4 float4 loads
    const float4* W24 = (const float4*)W2;
    float r0 = 0.f, r1 = 0.f;
    #pragma unroll
    for (int k = 0; k < 4; ++k) {
        float4 wq = W24[li * 4 + k];         // rows li*8+2k (x,y), li*8+2k+1 (z,w)
        r0 += v[2 * k] * wq.x + v[2 * k + 1] * wq.z;
        r1 += v[2 * k] * wq.y + v[2 * k + 1] * wq.w;
    }
    #pragma unroll
    for (int off = 1; off < 8; off <<= 1) {
        r0 += __shfl_xor(r0, off);
        r1 += __shfl_xor(r1, off);
    }
    if (li == 0) *(float2*)&h2[(size_t)n * EMB] = make_float2(r0 * di, r1 * di);  // h2' = dinv*h2
}

// ---------------------------------------------------------------------------
// Fused layer-2 CSR gather (pure sum of h2') + b2 + global mean pool
// + last-block finalize (done-counter, no spinning; validated in R3 run).
__global__ __launch_bounds__(256) void agg2_pool_final_kernel(
        const int* __restrict__ rowptr, const int* __restrict__ csr,
        const float* __restrict__ h2,
        const float* __restrict__ dinv, const float* __restrict__ b2,
        const int* __restrict__ batch,
        float* __restrict__ sums, float* __restrict__ cntf, int* __restrict__ done1,
        float* __restrict__ out, int N, int G) {
    int n = blockIdx.x * blockDim.x + threadIdx.x;
    int lane = threadIdx.x & 63;
    const float2* h2v = (const float2*)h2;
    float v0 = 0.f, v1 = 0.f, c = 0.f;
    int g = -1;
    if (n < N) {
        float di = dinv[n];
        float2 hs = h2v[n];
        v0 = hs.x; v1 = hs.y;
        int j0 = rowptr[n], j1 = rowptr[n + 1];
        int j = j0;
        for (; j + 7 < j1; j += 8) {
            int s0 = csr[j],     s1 = csr[j + 1], s2 = csr[j + 2], s3 = csr[j + 3];
            int s4 = csr[j + 4], s5 = csr[j + 5], s6 = csr[j + 6], s7 = csr[j + 7];
            float2 a = h2v[s0], b = h2v[s1], cc = h2v[s2], d = h2v[s3];
            float2 e = h2v[s4], f = h2v[s5], gg2 = h2v[s6], h = h2v[s7];
            v0 += a.x + b.x + cc.x + d.x;
            v1 += a.y + b.y + cc.y + d.y;
            v0 += e.x + f.x + gg2.x + h.x;
            v1 += e.y + f.y + gg2.y + h.y;
        }
        for (; j + 3 < j1; j += 4) {
            int s0 = csr[j], s1 = csr[j + 1], s2 = csr[j + 2], s3 = csr[j + 3];
            float2 a = h2v[s0], b = h2v[s1], cc = h2v[s2], d = h2v[s3];
            v0 += a.x + b.x + cc.x + d.x;
            v1 += a.y + b.y + cc.y + d.y;
        }
        for (; j < j1; ++j) {
            float2 hv = h2v[csr[j]];
            v0 += hv.x; v1 += hv.y;
        }
        v0 = di * v0 + b2[0];
        v1 = di * v1 + b2[1];
        g = batch[n];
        c = 1.f;
    }
    #pragma unroll
    for (int off = 1; off < 64; off <<= 1) {
        int gg = __shfl_up(g, off);
        float t0 = __shfl_up(v0, off);
        float t1 = __shfl_up(v1, off);
        float tc = __shfl_up(c, off);
        if (lane >= off && gg == g) { v0 += t0; v1 += t1; c += tc; }
    }
    int gn = __shfl_down(g, 1);
    if (g >= 0 && (lane == 63 || gn != g)) {
        atomicAdd(&sums[g * EMB + 0], v0);
        atomicAdd(&sums[g * EMB + 1], v1);
        atomicAdd(&cntf[g], c);
    }

    // last-block finalize (device-scope done counter; no dispatch-order assumption)
    __shared__ int sdone;
    __threadfence();
    if (threadIdx.x == 0) sdone = atomicAdd(done1, 1);
    __syncthreads();
    if (sdone == (int)gridDim.x - 1) {
        for (int i = threadIdx.x; i < G; i += 256) {
            float s0 = atomicAdd(&sums[i * EMB + 0], 0.f);   // coherent read
            float s1 = atomicAdd(&sums[i * EMB + 1], 0.f);
            float cc = fmaxf(atomicAdd(&cntf[i], 0.f), 1.0f);
            out[i * EMB + 0] = s0 / cc;
            out[i * EMB + 1] = s1 / cc;
        }
    }
}

// ---------------------------------------------------------------------------
extern "C" void kernel_launch(void* const* d_in, const int* in_sizes, int n_in,
                              void* d_out, int out_size, void* d_ws, size_t ws_size,
                              hipStream_t stream) {
    const float* x     = (const float*)d_in[0];
    const int*   ei    = (const int*)d_in[1];
    const int*   batch = (const int*)d_in[2];
    const float* W1    = (const float*)d_in[3];
    const float* b1    = (const float*)d_in[4];
    const float* W2    = (const float*)d_in[5];
    const float* b2    = (const float*)d_in[6];
    float* out = (float*)d_out;

    const int N = in_sizes[0] / FIN;   // 100000
    const int E = in_sizes[1] / 2;     // 1600000
    const int G = out_size / EMB;      // 512
    const int* src = ei;
    const int* dst = ei + E;

    const int NBK = (N + BKSZ - 1) / BKSZ;                    // 196 coarse buckets
    const int chunk = (((E + NBLK - 1) / NBLK) + 3) & ~3;     // x4 -> 16B-aligned slices

    // ---- workspace layout (16 B aligned chunks) ----
    char* p = (char*)d_ws;
    auto take = [&](size_t bytes) { char* r = p; p += (bytes + 15) & ~(size_t)15; return r; };
    int*      counts = (int*)take(sizeof(int) * NBK * NBLK);
    int*      btot   = (int*)take(sizeof(int) * NBK);
    int*      bucketBase = (int*)take(sizeof(int) * (NBK + 1));
    unsigned* ebuf   = (unsigned*)take(sizeof(unsigned) * E);
    int*      csr    = (int*)take(sizeof(int) * E);
    int*      rowptr = (int*)take(sizeof(int) * (N + 1));
    float*    dinv   = (float*)take(sizeof(float) * N);
    unsigned short* h1b = (unsigned short*)take(sizeof(unsigned short) * (size_t)N * HID);
    float*    h2     = (float*)take(sizeof(float) * (size_t)N * EMB);
    float*    pool   = (float*)take(sizeof(float) * 3 * G);   // sums | cntf
    int*      done   = (int*)take(sizeof(int) * 4);           // done-counter
    __bf16*   Bh     = (__bf16*)take(sizeof(__bf16) * 4 * 8 * 64 * 8);  // 32 KB
    __bf16*   Bl     = (__bf16*)take(sizeof(__bf16) * 4 * 8 * 64 * 8);  // 32 KB
    float*    sums   = pool;
    float*    cntf   = pool + 2 * G;

    // 1. CSR build: hist(+W1 pre-pack, +done-zero) -> 2-level bucket scan
    //    (+zero pool) -> scatter -> build
    bin_hist_kernel<<<NBLK + WPREP, 256, 0, stream>>>(dst, counts, W1, Bh, Bl,
                                                      done, E, chunk, NBK);
    scan_local_kernel<<<NBK, 256, 0, stream>>>(counts, btot);
    scan_tot_kernel<<<1, 256, 0, stream>>>(btot, bucketBase, pool, NBK, 3 * G);
    bin_scatter_kernel<<<NBLK, 256, 0, stream>>>(src, dst, counts, bucketBase, ebuf, E, chunk, NBK);
    build_kernel<<<NBK, 256, 0, stream>>>(ebuf, bucketBase, rowptr, dinv, csr, N, E);
    // 2. h1' = dinv * (x @ W1)  (MFMA, pre-packed B frags, bf16 out, row-major)
    gemm1_kernel<<<(N + 63) / 64, 256, 0, stream>>>(x, Bh, Bl, dinv, h1b, N);
    // 3. fused agg1 + relu + W2 -> h2' = dinv*h2  (8 nodes/wave, 16 B/lane)
    agg1_layer2_kernel<<<(int)(((long)N * 8 + 255) / 256), 256, 0, stream>>>(
        rowptr, csr, h1b, dinv, b1, W2, h2, N);
    // 4. fused agg2 + pool + last-block finalize
    agg2_pool_final_kernel<<<(N + 255) / 256, 256, 0, stream>>>(
        rowptr, csr, h2, dinv, b2, batch, sums, cntf, done, out, N, G);
}

// Round 8
// 288.473 us; speedup vs baseline: 2.3365x; 1.0750x over previous
//
#include <hip/hip_runtime.h>
#include <hip/hip_bf16.h>

#define FIN 256
#define HID 64
#define EMB 2
#define BKB 9            // bucket = dst >> 9 (512 nodes per bucket)
#define BKSZ 512
#define MAXBK 256        // supports N <= 131072
#define NBLK 256         // blocks for binning passes
#define WPREP 8          // extra blocks in bin_hist grid that pre-pack W1

typedef __bf16 bf16x8 __attribute__((ext_vector_type(8)));
typedef float  f32x16 __attribute__((ext_vector_type(16)));
typedef unsigned short u16x8 __attribute__((ext_vector_type(8)));

// ---- bf16 helpers (RNE) ----
static __device__ __forceinline__ unsigned short f2bf(float f) {
    union { float f; unsigned int u; } v; v.f = f;
    unsigned int u = v.u;
    unsigned int r = (u + 0x7fffu + ((u >> 16) & 1u)) >> 16;
    return (unsigned short)r;
}
static __device__ __forceinline__ float bf2f(unsigned short h) {
    union { unsigned int u; float f; } v; v.u = ((unsigned int)h) << 16;
    return v.f;
}

// ---------------------------------------------------------------------------
// Pass A1: per-block histogram of coarse buckets (dst>>9) -> counts[bucket][block]
// int4 vector loads (chunk is a multiple of 4 -> each block slice is 16B-aligned).
// Blocks [NBLK, NBLK+WPREP) instead pre-pack W1 into bf16 hi/lo MFMA-fragment
// order (one-time; replaces per-block B staging in gemm1).
// Packed layout: vec index v = ((ch*8 + g)*64 + m), elem q:
//   k = ch*64 + (g&3)*16 + (m>>5)*8 + q,  n = (g>>2)*32 + (m&31)
__global__ __launch_bounds__(256) void bin_hist_kernel(
        const int* __restrict__ dst, int* __restrict__ counts,
        const float* __restrict__ W, __bf16* __restrict__ Bh, __bf16* __restrict__ Bl,
        int E, int chunk, int NBK) {
    if (blockIdx.x >= NBLK) {
        int t = (blockIdx.x - NBLK) * 256 + threadIdx.x;   // 0..2047
        int ch = t >> 9, g = (t >> 6) & 7, m = t & 63;
        int kbase = ch * 64 + (g & 3) * 16 + ((m >> 5) << 3);
        int n = ((g >> 2) << 5) + (m & 31);
        bf16x8 hi, lo;
        #pragma unroll
        for (int q = 0; q < 8; ++q) {
            float w = W[(size_t)(kbase + q) * HID + n];
            __bf16 h = (__bf16)w;
            hi[q] = h; lo[q] = (__bf16)(w - (float)h);
        }
        *(bf16x8*)&Bh[(size_t)t * 8] = hi;
        *(bf16x8*)&Bl[(size_t)t * 8] = lo;
        return;
    }
    __shared__ int hist[MAXBK];
    int tid = threadIdx.x;
    for (int b = tid; b < NBK; b += 256) hist[b] = 0;
    __syncthreads();
    int e0 = blockIdx.x * chunk, e1 = min(e0 + chunk, E);
    if (e0 < e1) {
        const int4* d4 = (const int4*)(dst + e0);
        int nv = (e1 - e0) >> 2;
        for (int i = tid; i < nv; i += 256) {
            int4 v = d4[i];
            atomicAdd(&hist[v.x >> BKB], 1);
            atomicAdd(&hist[v.y >> BKB], 1);
            atomicAdd(&hist[v.z >> BKB], 1);
            atomicAdd(&hist[v.w >> BKB], 1);
        }
        for (int i = e0 + (nv << 2) + tid; i < e1; i += 256)
            atomicAdd(&hist[dst[i] >> BKB], 1);
    }
    __syncthreads();
    for (int b = tid; b < NBK; b += 256) counts[b * NBLK + blockIdx.x] = hist[b];
}

// Scan 1/2: per-bucket exclusive scan of its 256 per-block counts (in place)
// + bucket total. One block per bucket.
__global__ __launch_bounds__(256) void scan_local_kernel(
        int* __restrict__ counts, int* __restrict__ btot) {
    __shared__ int s[256];
    const int b = blockIdx.x, tid = threadIdx.x;
    int v = counts[b * NBLK + tid];
    s[tid] = v;
    __syncthreads();
    for (int off = 1; off < 256; off <<= 1) {
        int t = (tid >= off) ? s[tid - off] : 0;
        __syncthreads();
        s[tid] += t;
        __syncthreads();
    }
    counts[b * NBLK + tid] = s[tid] - v;   // exclusive within bucket
    if (tid == 255) btot[b] = s[255];
}

// Scan 2/2: single block scans bucket totals -> bucketBase[0..NBK]; also zeroes
// the pool accumulators (sums[G*2] + cntf[G]).
__global__ __launch_bounds__(256) void scan_tot_kernel(
        const int* __restrict__ btot, int* __restrict__ bucketBase,
        float* __restrict__ sums, int NBK, int nzero) {
    __shared__ int s[256];
    const int tid = threadIdx.x;
    int v = (tid < NBK) ? btot[tid] : 0;
    s[tid] = v;
    __syncthreads();
    for (int off = 1; off < 256; off <<= 1) {
        int t = (tid >= off) ? s[tid - off] : 0;
        __syncthreads();
        s[tid] += t;
        __syncthreads();
    }
    if (tid < NBK) bucketBase[tid] = s[tid] - v;
    if (tid == NBK - 1) bucketBase[NBK] = s[tid];
    for (int i = tid; i < nzero; i += 256) sums[i] = 0.f;
}

// Pass A2: scatter packed (src<<9 | dst&511) into per-(bucket,block) runs.
__global__ __launch_bounds__(256) void bin_scatter_kernel(
        const int* __restrict__ src, const int* __restrict__ dst,
        const int* __restrict__ counts, const int* __restrict__ bucketBase,
        unsigned* __restrict__ ebuf, int E, int chunk, int NBK) {
    __shared__ int cur[MAXBK];
    int tid = threadIdx.x;
    for (int b = tid; b < NBK; b += 256)
        cur[b] = bucketBase[b] + counts[b * NBLK + blockIdx.x];
    __syncthreads();
    int e0 = blockIdx.x * chunk, e1 = min(e0 + chunk, E);
    if (e0 >= e1) return;
    const int4* s4 = (const int4*)(src + e0);
    const int4* d4 = (const int4*)(dst + e0);
    int nv = (e1 - e0) >> 2;
    for (int i = tid; i < nv; i += 256) {
        int4 sv = s4[i], dv = d4[i];
        int b0 = dv.x >> BKB;
        int p0 = atomicAdd(&cur[b0], 1);
        ebuf[p0] = ((unsigned)sv.x << BKB) | (unsigned)(dv.x & (BKSZ - 1));
        int b1 = dv.y >> BKB;
        int p1 = atomicAdd(&cur[b1], 1);
        ebuf[p1] = ((unsigned)sv.y << BKB) | (unsigned)(dv.y & (BKSZ - 1));
        int b2 = dv.z >> BKB;
        int p2 = atomicAdd(&cur[b2], 1);
        ebuf[p2] = ((unsigned)sv.z << BKB) | (unsigned)(dv.z & (BKSZ - 1));
        int b3 = dv.w >> BKB;
        int p3 = atomicAdd(&cur[b3], 1);
        ebuf[p3] = ((unsigned)sv.w << BKB) | (unsigned)(dv.w & (BKSZ - 1));
    }
    for (int i = e0 + (nv << 2) + tid; i < e1; i += 256) {
        int s = src[i], d = dst[i];
        int b = d >> BKB;
        int pos = atomicAdd(&cur[b], 1);
        ebuf[pos] = ((unsigned)s << BKB) | (unsigned)(d & (BKSZ - 1));
    }
}

// Pass B: one block per bucket -> degree/dinv/rowptr + bucket-local CSR scatter
__global__ __launch_bounds__(256) void build_kernel(
        const unsigned* __restrict__ ebuf, const int* __restrict__ bucketBase,
        int* __restrict__ rowptr, float* __restrict__ dinv, int* __restrict__ csr,
        int N, int E) {
    __shared__ int hist[BKSZ];
    __shared__ int scanb[256];
    __shared__ int cur[BKSZ];
    const int b = blockIdx.x, tid = threadIdx.x;
    const int r0 = bucketBase[b];
    const int r1 = bucketBase[b + 1];
    const int nb0 = b * BKSZ;

    hist[tid] = 0; hist[tid + 256] = 0;
    __syncthreads();
    for (int i = r0 + tid; i < r1; i += 256)
        atomicAdd(&hist[ebuf[i] & (BKSZ - 1u)], 1);
    __syncthreads();

    int h0 = hist[2 * tid], h1 = hist[2 * tid + 1];
    if (nb0 + 2 * tid < N)     dinv[nb0 + 2 * tid]     = rsqrtf((float)h0 + 1.f);
    if (nb0 + 2 * tid + 1 < N) dinv[nb0 + 2 * tid + 1] = rsqrtf((float)h1 + 1.f);
    scanb[tid] = h0 + h1;
    __syncthreads();
    for (int off = 1; off < 256; off <<= 1) {
        int t = (tid >= off) ? scanb[tid - off] : 0;
        __syncthreads();
        scanb[tid] += t;
        __syncthreads();
    }
    int base0 = scanb[tid] - (h0 + h1);
    int o0 = base0, o1 = base0 + h0;
    cur[2 * tid] = o0; cur[2 * tid + 1] = o1;
    if (nb0 + 2 * tid < N)     rowptr[nb0 + 2 * tid]     = r0 + o0;
    if (nb0 + 2 * tid + 1 < N) rowptr[nb0 + 2 * tid + 1] = r0 + o1;
    if (nb0 + BKSZ >= N && tid == 0) rowptr[N] = E;
    __syncthreads();
    for (int i = r0 + tid; i < r1; i += 256) {
        unsigned u = ebuf[i];
        int loc = (int)(u & (BKSZ - 1u));
        int p = atomicAdd(&cur[loc], 1);
        csr[r0 + p] = (int)(u >> BKB);
    }
}

// ---------------------------------------------------------------------------
// h1' = dinv * (x @ W1) via MFMA (bf16 hi/lo split: xh*wh + xh*wl + xl*wh).
// Block = 64-node x 64-feat tile, 4 waves = four 32x32 quadrants. bf16 store.
// B fragments come pre-packed (hi/lo, MFMA order) from global: 32 KB, L2-hot,
// coalesced bf16x8/lane -> no B LDS, no per-block W conversion. LDS 16 KB.
__global__ __launch_bounds__(256) void gemm1_kernel(
        const float* __restrict__ x,
        const __bf16* __restrict__ Bh, const __bf16* __restrict__ Bl,
        const float* __restrict__ dinv, unsigned short* __restrict__ h1b, int N) {
    __shared__ __align__(16) __bf16 A_hi[2 * 4 * 64 * 8];
    __shared__ __align__(16) __bf16 A_lo[2 * 4 * 64 * 8];

    const int tid = threadIdx.x;
    const int base = blockIdx.x * 64;
    const int w = tid >> 6;
    const int l = tid & 63;
    const int mg = w >> 1, ng = w & 1;

    const bf16x8* Bh8 = (const bf16x8*)Bh;
    const bf16x8* Bl8 = (const bf16x8*)Bl;

    f32x16 acc = {};

    const int r  = tid & 63;
    const int ks = tid >> 6;
    const int rl = r & 31, rh = r >> 5;

    for (int ch = 0; ch < 4; ++ch) {
        const int ck0 = ch * 64;
        __syncthreads();
        {
            int row = base + r;
            float f[16];
            if (row < N) {
                const float* xp = &x[(size_t)row * FIN + ck0 + ks * 16];
                float4 v0 = *(const float4*)(xp + 0);
                float4 v1 = *(const float4*)(xp + 4);
                float4 v2 = *(const float4*)(xp + 8);
                float4 v3 = *(const float4*)(xp + 12);
                f[0]=v0.x; f[1]=v0.y; f[2]=v0.z; f[3]=v0.w;
                f[4]=v1.x; f[5]=v1.y; f[6]=v1.z; f[7]=v1.w;
                f[8]=v2.x; f[9]=v2.y; f[10]=v2.z; f[11]=v2.w;
                f[12]=v3.x; f[13]=v3.y; f[14]=v3.z; f[15]=v3.w;
            } else {
                #pragma unroll
                for (int q = 0; q < 16; ++q) f[q] = 0.f;
            }
            bf16x8 ha, hb, la, lb;
            #pragma unroll
            for (int q = 0; q < 8; ++q) {
                __bf16 h0 = (__bf16)f[q];
                ha[q] = h0; la[q] = (__bf16)(f[q] - (float)h0);
                __bf16 h1v = (__bf16)f[q + 8];
                hb[q] = h1v; lb[q] = (__bf16)(f[q + 8] - (float)h1v);
            }
            int ra = ((rh * 4 + ks) * 64 + rl) * 8;
            int rb = ((rh * 4 + ks) * 64 + 32 + rl) * 8;
            *(bf16x8*)&A_hi[ra] = ha; *(bf16x8*)&A_hi[rb] = hb;
            *(bf16x8*)&A_lo[ra] = la; *(bf16x8*)&A_lo[rb] = lb;
        }
        __syncthreads();

        #pragma unroll
        for (int s = 0; s < 4; ++s) {
            bf16x8 a_h = *(const bf16x8*)&A_hi[((mg * 4 + s) * 64 + l) * 8];
            bf16x8 a_l = *(const bf16x8*)&A_lo[((mg * 4 + s) * 64 + l) * 8];
            int bv = (ch * 8 + ng * 4 + s) * 64 + l;
            bf16x8 b_h = Bh8[bv];
            bf16x8 b_l = Bl8[bv];
            acc = __builtin_amdgcn_mfma_f32_32x32x16_bf16(a_h, b_h, acc, 0, 0, 0);
            acc = __builtin_amdgcn_mfma_f32_32x32x16_bf16(a_h, b_l, acc, 0, 0, 0);
            acc = __builtin_amdgcn_mfma_f32_32x32x16_bf16(a_l, b_h, acc, 0, 0, 0);
        }
    }

    const int col = l & 31;
    const int rbase = 4 * (l >> 5);
    #pragma unroll
    for (int reg = 0; reg < 16; ++reg) {
        int row = (reg & 3) + 8 * (reg >> 2) + rbase;
        int node = base + mg * 32 + row;
        if (node < N)
            h1b[(size_t)node * HID + ng * 32 + col] = f2bf(acc[reg] * dinv[node]);
    }
}

// ---------------------------------------------------------------------------
// Fused layer-1 CSR gather (pure sum of pre-scaled h1') + b1 + ReLU + (64->2).
// 8 nodes per wave: 8 lanes/node, lane = 8 feats (ushort8 = 16 B/lane gather ->
// 1 KiB / 8 random lines per wave VMEM instruction). Unroll-8 main loop keeps
// 8 independent gathers in flight; summation grouped exactly as two unroll-4
// bodies so the f32 association (and absmax) is bit-identical.
__global__ __launch_bounds__(256) void agg1_layer2_kernel(
        const int* __restrict__ rowptr, const int* __restrict__ csr,
        const unsigned short* __restrict__ h1b,
        const float* __restrict__ dinv, const float* __restrict__ b1,
        const float* __restrict__ W2, float* __restrict__ h2, int N) {
    long t = (long)blockIdx.x * blockDim.x + threadIdx.x;
    int n = (int)(t >> 3);
    int li = threadIdx.x & 7;
    if (n >= N) return;
    const u16x8* h18 = (const u16x8*)h1b;    // row = 8 vectors x 8 feats

    float di = dinv[n];
    u16x8 sl = h18[(size_t)n * 8 + li];      // self term (h1' pre-scaled)
    float v[8];
    #pragma unroll
    for (int k = 0; k < 8; ++k) v[k] = bf2f(sl[k]);

    int j0 = rowptr[n], j1 = rowptr[n + 1];
    int j = j0;
    for (; j + 7 < j1; j += 8) {
        int s0 = csr[j],     s1 = csr[j + 1], s2 = csr[j + 2], s3 = csr[j + 3];
        int s4 = csr[j + 4], s5 = csr[j + 5], s6 = csr[j + 6], s7 = csr[j + 7];
        u16x8 g0 = h18[(size_t)s0 * 8 + li];
        u16x8 g1 = h18[(size_t)s1 * 8 + li];
        u16x8 g2 = h18[(size_t)s2 * 8 + li];
        u16x8 g3 = h18[(size_t)s3 * 8 + li];
        u16x8 g4 = h18[(size_t)s4 * 8 + li];
        u16x8 g5 = h18[(size_t)s5 * 8 + li];
        u16x8 g6 = h18[(size_t)s6 * 8 + li];
        u16x8 g7 = h18[(size_t)s7 * 8 + li];
        #pragma unroll
        for (int k = 0; k < 8; ++k) {
            v[k] += bf2f(g0[k]) + bf2f(g1[k]) + bf2f(g2[k]) + bf2f(g3[k]);
            v[k] += bf2f(g4[k]) + bf2f(g5[k]) + bf2f(g6[k]) + bf2f(g7[k]);
        }
    }
    for (; j + 3 < j1; j += 4) {
        int s0 = csr[j], s1 = csr[j + 1], s2 = csr[j + 2], s3 = csr[j + 3];
        u16x8 g0 = h18[(size_t)s0 * 8 + li];
        u16x8 g1 = h18[(size_t)s1 * 8 + li];
        u16x8 g2 = h18[(size_t)s2 * 8 + li];
        u16x8 g3 = h18[(size_t)s3 * 8 + li];
        #pragma unroll
        for (int k = 0; k < 8; ++k)
            v[k] += bf2f(g0[k]) + bf2f(g1[k]) + bf2f(g2[k]) + bf2f(g3[k]);
    }
    for (; j < j1; ++j) {
        u16x8 g = h18[(size_t)csr[j] * 8 + li];
        #pragma unroll
        for (int k = 0; k < 8; ++k) v[k] += bf2f(g[k]);
    }

    // bias + ReLU (feats f = li*8 + k)
    const float4 ba = *(const float4*)&b1[li * 8];
    const float4 bb = *(const float4*)&b1[li * 8 + 4];
    v[0] = fmaxf(di * v[0] + ba.x, 0.f); v[1] = fmaxf(di * v[1] + ba.y, 0.f);
    v[2] = fmaxf(di * v[2] + ba.z, 0.f); v[3] = fmaxf(di * v[3] + ba.w, 0.f);
    v[4] = fmaxf(di * v[4] + bb.x, 0.f); v[5] = fmaxf(di * v[5] + bb.y, 0.f);
    v[6] = fmaxf(di * v[6] + bb.z, 0.f); v[7] = fmaxf(di * v[7] + bb.w, 0.f);

    // W2 rows li*8 .. li*8+7 (each row = 2 floats): 4 float4 loads
    const float4* W24 = (const float4*)W2;
    float r0 = 0.f, r1 = 0.f;
    #pragma unroll
    for (int k = 0; k < 4; ++k) {
        float4 wq = W24[li * 4 + k];         // rows li*8+2k (x,y), li*8+2k+1 (z,w)
        r0 += v[2 * k] * wq.x + v[2 * k + 1] * wq.z;
        r1 += v[2 * k] * wq.y + v[2 * k + 1] * wq.w;
    }
    #pragma unroll
    for (int off = 1; off < 8; off <<= 1) {
        r0 += __shfl_xor(r0, off);
        r1 += __shfl_xor(r1, off);
    }
    if (li == 0) *(float2*)&h2[(size_t)n * EMB] = make_float2(r0 * di, r1 * di);  // h2' = dinv*h2
}

// ---------------------------------------------------------------------------
// Fused layer-2 CSR gather (pure sum of h2') + b2 + global mean pool.
__global__ __launch_bounds__(256) void agg2_pool_kernel(
        const int* __restrict__ rowptr, const int* __restrict__ csr,
        const float* __restrict__ h2,
        const float* __restrict__ dinv, const float* __restrict__ b2,
        const int* __restrict__ batch,
        float* __restrict__ sums, float* __restrict__ cntf, int N) {
    int n = blockIdx.x * blockDim.x + threadIdx.x;
    int lane = threadIdx.x & 63;
    const float2* h2v = (const float2*)h2;
    float v0 = 0.f, v1 = 0.f, c = 0.f;
    int g = -1;
    if (n < N) {
        float di = dinv[n];
        float2 hs = h2v[n];
        v0 = hs.x; v1 = hs.y;
        int j0 = rowptr[n], j1 = rowptr[n + 1];
        int j = j0;
        for (; j + 7 < j1; j += 8) {
            int s0 = csr[j],     s1 = csr[j + 1], s2 = csr[j + 2], s3 = csr[j + 3];
            int s4 = csr[j + 4], s5 = csr[j + 5], s6 = csr[j + 6], s7 = csr[j + 7];
            float2 a = h2v[s0], b = h2v[s1], cc = h2v[s2], d = h2v[s3];
            float2 e = h2v[s4], f = h2v[s5], gg2 = h2v[s6], h = h2v[s7];
            v0 += a.x + b.x + cc.x + d.x;
            v1 += a.y + b.y + cc.y + d.y;
            v0 += e.x + f.x + gg2.x + h.x;
            v1 += e.y + f.y + gg2.y + h.y;
        }
        for (; j + 3 < j1; j += 4) {
            int s0 = csr[j], s1 = csr[j + 1], s2 = csr[j + 2], s3 = csr[j + 3];
            float2 a = h2v[s0], b = h2v[s1], cc = h2v[s2], d = h2v[s3];
            v0 += a.x + b.x + cc.x + d.x;
            v1 += a.y + b.y + cc.y + d.y;
        }
        for (; j < j1; ++j) {
            float2 hv = h2v[csr[j]];
            v0 += hv.x; v1 += hv.y;
        }
        v0 = di * v0 + b2[0];
        v1 = di * v1 + b2[1];
        g = batch[n];
        c = 1.f;
    }
    #pragma unroll
    for (int off = 1; off < 64; off <<= 1) {
        int gg = __shfl_up(g, off);
        float t0 = __shfl_up(v0, off);
        float t1 = __shfl_up(v1, off);
        float tc = __shfl_up(c, off);
        if (lane >= off && gg == g) { v0 += t0; v1 += t1; c += tc; }
    }
    int gn = __shfl_down(g, 1);
    if (g >= 0 && (lane == 63 || gn != g)) {
        atomicAdd(&sums[g * EMB + 0], v0);
        atomicAdd(&sums[g * EMB + 1], v1);
        atomicAdd(&cntf[g], c);
    }
}

__global__ void final_kernel(const float* __restrict__ sums, const float* __restrict__ cntf,
                             float* __restrict__ out, int G) {
    int g = blockIdx.x * blockDim.x + threadIdx.x;
    if (g >= G) return;
    float c = fmaxf(cntf[g], 1.0f);
    out[g * EMB + 0] = sums[g * EMB + 0] / c;
    out[g * EMB + 1] = sums[g * EMB + 1] / c;
}

// ---------------------------------------------------------------------------
extern "C" void kernel_launch(void* const* d_in, const int* in_sizes, int n_in,
                              void* d_out, int out_size, void* d_ws, size_t ws_size,
                              hipStream_t stream) {
    const float* x     = (const float*)d_in[0];
    const int*   ei    = (const int*)d_in[1];
    const int*   batch = (const int*)d_in[2];
    const float* W1    = (const float*)d_in[3];
    const float* b1    = (const float*)d_in[4];
    const float* W2    = (const float*)d_in[5];
    const float* b2    = (const float*)d_in[6];
    float* out = (float*)d_out;

    const int N = in_sizes[0] / FIN;   // 100000
    const int E = in_sizes[1] / 2;     // 1600000
    const int G = out_size / EMB;      // 512
    const int* src = ei;
    const int* dst = ei + E;

    const int NBK = (N + BKSZ - 1) / BKSZ;                    // 196 coarse buckets
    const int chunk = (((E + NBLK - 1) / NBLK) + 3) & ~3;     // x4 -> 16B-aligned slices

    // ---- workspace layout (16 B aligned chunks) ----
    char* p = (char*)d_ws;
    auto take = [&](size_t bytes) { char* r = p; p += (bytes + 15) & ~(size_t)15; return r; };
    int*      counts = (int*)take(sizeof(int) * NBK * NBLK);
    int*      btot   = (int*)take(sizeof(int) * NBK);
    int*      bucketBase = (int*)take(sizeof(int) * (NBK + 1));
    unsigned* ebuf   = (unsigned*)take(sizeof(unsigned) * E);
    int*      csr    = (int*)take(sizeof(int) * E);
    int*      rowptr = (int*)take(sizeof(int) * (N + 1));
    float*    dinv   = (float*)take(sizeof(float) * N);
    unsigned short* h1b = (unsigned short*)take(sizeof(unsigned short) * (size_t)N * HID);
    float*    h2     = (float*)take(sizeof(float) * (size_t)N * EMB);
    float*    sums   = (float*)take(sizeof(float) * G * EMB);
    float*    cntf   = (float*)take(sizeof(float) * G);
    __bf16*   Bh     = (__bf16*)take(sizeof(__bf16) * 4 * 8 * 64 * 8);  // 32 KB
    __bf16*   Bl     = (__bf16*)take(sizeof(__bf16) * 4 * 8 * 64 * 8);  // 32 KB

    // 1. CSR build: hist(+W1 pre-pack) -> 2-level bucket scan (+zero sums)
    //    -> scatter -> build
    bin_hist_kernel<<<NBLK + WPREP, 256, 0, stream>>>(dst, counts, W1, Bh, Bl, E, chunk, NBK);
    scan_local_kernel<<<NBK, 256, 0, stream>>>(counts, btot);
    scan_tot_kernel<<<1, 256, 0, stream>>>(btot, bucketBase, sums, NBK, 3 * G);
    bin_scatter_kernel<<<NBLK, 256, 0, stream>>>(src, dst, counts, bucketBase, ebuf, E, chunk, NBK);
    build_kernel<<<NBK, 256, 0, stream>>>(ebuf, bucketBase, rowptr, dinv, csr, N, E);
    // 2. h1' = dinv * (x @ W1)  (MFMA, pre-packed B frags, bf16 out, row-major)
    gemm1_kernel<<<(N + 63) / 64, 256, 0, stream>>>(x, Bh, Bl, dinv, h1b, N);
    // 3. fused agg1 + relu + W2 -> h2' = dinv*h2  (8 nodes/wave, 16 B/lane)
    agg1_layer2_kernel<<<(int)(((long)N * 8 + 255) / 256), 256, 0, stream>>>(
        rowptr, csr, h1b, dinv, b1, W2, h2, N);
    // 4. fused agg2 + pool, then finalize
    agg2_pool_kernel<<<(N + 255) / 256, 256, 0, stream>>>(
        rowptr, csr, h2, dinv, b2, batch, sums, cntf, N);
    final_kernel<<<(G + 255) / 256, 256, 0, stream>>>(sums, cntf, out, G);
}